// Round 1
// baseline (771.854 us; speedup 1.0000x reference)
//
#include <hip/hip_runtime.h>

#define NN 50000
#define EE 800000
#define DIN 256
#define H 128
#define MM 64
#define CC 4
#define BB 128
#define NHEAD 8
#define HDIM 16

#define SCAN_CHUNK 1024
#define NB ((NN + SCAN_CHUNK - 1) / SCAN_CHUNK)   // 49

// ---------------- CSR build ----------------

__global__ void count_deg(const int* __restrict__ col, int* __restrict__ degcnt) {
    int e = blockIdx.x * blockDim.x + threadIdx.x;
    if (e < EE) atomicAdd(&degcnt[col[e]], 1);
}

__global__ void scan_a(const int* __restrict__ degcnt, int* __restrict__ offs,
                       int* __restrict__ bsums) {
    __shared__ int lds[256];
    int t = threadIdx.x;
    int base = blockIdx.x * SCAN_CHUNK + t * 4;
    int v[4]; int s = 0;
    #pragma unroll
    for (int i = 0; i < 4; i++) {
        int ix = base + i;
        v[i] = (ix < NN) ? degcnt[ix] : 0;
        s += v[i];
    }
    lds[t] = s; __syncthreads();
    for (int off = 1; off < 256; off <<= 1) {
        int x = (t >= off) ? lds[t - off] : 0;
        __syncthreads();
        lds[t] += x;
        __syncthreads();
    }
    int incl = lds[t];
    int excl = incl - s;
    if (t == 255) bsums[blockIdx.x] = incl;
    int run = excl;
    #pragma unroll
    for (int i = 0; i < 4; i++) {
        int ix = base + i;
        if (ix < NN) offs[ix] = run;
        run += v[i];
    }
}

__global__ void scan_b(int* __restrict__ bsums) {
    if (threadIdx.x == 0 && blockIdx.x == 0) {
        int run = 0;
        for (int i = 0; i < NB; i++) { int x = bsums[i]; bsums[i] = run; run += x; }
    }
}

__global__ void scan_c(int* __restrict__ offs, const int* __restrict__ bsums,
                       const int* __restrict__ degcnt, int* __restrict__ cursor,
                       float* __restrict__ dis) {
    int v = blockIdx.x * blockDim.x + threadIdx.x;
    if (v < NN) {
        int o = offs[v] + bsums[v / SCAN_CHUNK];
        offs[v] = o;
        cursor[v] = o;
        dis[v] = rsqrtf((float)(degcnt[v] + 1));   // +1 self loop
    }
}

__global__ void fill_csr(const int* __restrict__ row, const int* __restrict__ col,
                         int* __restrict__ cursor, int* __restrict__ csr) {
    int e = blockIdx.x * blockDim.x + threadIdx.x;
    if (e < EE) {
        int u = row[e], v = col[e];
        int p = atomicAdd(&cursor[v], 1);
        csr[p] = u;
    }
}

// ---------------- Linear (+ReLU, optionally +LayerNorm) ----------------
// out[r][j] = act( sum_k A[r][k] * W[k][j] + bias[j] )
// block = 256 threads (4 waves), 16 rows per block; wave w owns rows w*4..w*4+3;
// lane l owns cols {2l, 2l+1}. W staged in LDS in K-chunks of 64.

template <int K, bool LN>
__launch_bounds__(256)
__global__ void linear_kernel(const float* __restrict__ A, const float* __restrict__ W,
                              const float* __restrict__ bias,
                              const float* __restrict__ ln_g, const float* __restrict__ ln_b,
                              float* __restrict__ out) {
    constexpr int ROWS = 16, KC = 64;
    __shared__ __align__(16) float w_lds[KC * H];
    __shared__ __align__(16) float x_lds[ROWS * K];
    int t = threadIdx.x;
    int wv = t >> 6, l = t & 63;
    int rowBase = blockIdx.x * ROWS;
    int r0 = wv * 4;
    int c0 = 2 * l;

    // stage A rows (contiguous, float4)
    {
        const float4* src = reinterpret_cast<const float4*>(A + (size_t)rowBase * K);
        float4* dst = reinterpret_cast<float4*>(x_lds);
        for (int i = t; i < ROWS * K / 4; i += 256) dst[i] = src[i];
    }

    float acc[4][2] = {{0.f,0.f},{0.f,0.f},{0.f,0.f},{0.f,0.f}};

    for (int kc = 0; kc < K; kc += KC) {
        __syncthreads();
        {
            const float4* src = reinterpret_cast<const float4*>(W + (size_t)kc * H);
            float4* dst = reinterpret_cast<float4*>(w_lds);
            for (int i = t; i < KC * H / 4; i += 256) dst[i] = src[i];
        }
        __syncthreads();
        #pragma unroll 8
        for (int k = 0; k < KC; k++) {
            float2 wv2 = *reinterpret_cast<const float2*>(&w_lds[k * H + c0]);
            #pragma unroll
            for (int r = 0; r < 4; r++) {
                float xv = x_lds[(r0 + r) * K + kc + k];
                acc[r][0] = fmaf(xv, wv2.x, acc[r][0]);
                acc[r][1] = fmaf(xv, wv2.y, acc[r][1]);
            }
        }
    }

    float b0 = bias[c0], b1 = bias[c0 + 1];
    if constexpr (LN) {
        float g0 = ln_g[c0], g1 = ln_g[c0 + 1];
        float lb0 = ln_b[c0], lb1 = ln_b[c0 + 1];
        #pragma unroll
        for (int r = 0; r < 4; r++) {
            float v0 = fmaxf(acc[r][0] + b0, 0.f);
            float v1 = fmaxf(acc[r][1] + b1, 0.f);
            float s = v0 + v1, sq = v0 * v0 + v1 * v1;
            #pragma unroll
            for (int m = 1; m < 64; m <<= 1) {
                s  += __shfl_xor(s,  m, 64);
                sq += __shfl_xor(sq, m, 64);
            }
            float mean = s * (1.f / 128.f);
            float var  = sq * (1.f / 128.f) - mean * mean;
            float inv  = rsqrtf(var + 1e-5f);
            float o0 = (v0 - mean) * inv * g0 + lb0;
            float o1 = (v1 - mean) * inv * g1 + lb1;
            int rr = rowBase + r0 + r;
            reinterpret_cast<float2*>(out + (size_t)rr * H)[l] = make_float2(o0, o1);
        }
    } else {
        #pragma unroll
        for (int r = 0; r < 4; r++) {
            float v0 = fmaxf(acc[r][0] + b0, 0.f);
            float v1 = fmaxf(acc[r][1] + b1, 0.f);
            int rr = rowBase + r0 + r;
            reinterpret_cast<float2*>(out + (size_t)rr * H)[l] = make_float2(v0, v1);
        }
    }
}

// ---------------- GCN aggregation ----------------
// out[v] = dis[v] * ( sum_{u in in(v)} dis[u]*h[u]  +  dis[v]*h[v] )
// one wave per node; lane l owns cols {2l, 2l+1}

__launch_bounds__(256)
__global__ void agg_kernel(const float* __restrict__ h, const int* __restrict__ offs,
                           const int* __restrict__ degcnt, const int* __restrict__ csr,
                           const float* __restrict__ dis, float* __restrict__ out) {
    int wv = threadIdx.x >> 6, l = threadIdx.x & 63;
    int v = blockIdx.x * 4 + wv;
    if (v >= NN) return;
    float dv = dis[v];
    float2 self = reinterpret_cast<const float2*>(h + (size_t)v * H)[l];
    float ax = dv * self.x, ay = dv * self.y;
    int beg = offs[v], cnt = degcnt[v];

    // batch-load up to 64 neighbor indices / dis values into lanes, broadcast via shfl
    int   myu = (l < cnt) ? csr[beg + l] : 0;
    float myd = (l < cnt) ? dis[myu] : 0.f;
    int n0 = cnt < 64 ? cnt : 64;
    for (int i = 0; i < n0; i++) {
        int u = __shfl(myu, i, 64);
        float du = __shfl(myd, i, 64);
        float2 hu = reinterpret_cast<const float2*>(h + (size_t)u * H)[l];
        ax = fmaf(du, hu.x, ax);
        ay = fmaf(du, hu.y, ay);
    }
    for (int i = 64; i < cnt; i++) {
        int u = csr[beg + i];
        float du = dis[u];
        float2 hu = reinterpret_cast<const float2*>(h + (size_t)u * H)[l];
        ax = fmaf(du, hu.x, ax);
        ay = fmaf(du, hu.y, ay);
    }
    reinterpret_cast<float2*>(out + (size_t)v * H)[l] = make_float2(dv * ax, dv * ay);
}

// ---------------- mean pool (atomics) ----------------

__launch_bounds__(256)
__global__ void pool_kernel(const float* __restrict__ h, const int* __restrict__ batch,
                            float* __restrict__ sums, int* __restrict__ cnts) {
    int wv = threadIdx.x >> 6, l = threadIdx.x & 63;
    int v = blockIdx.x * 4 + wv;
    if (v >= NN) return;
    int b = batch[v];
    float2 hv = reinterpret_cast<const float2*>(h + (size_t)v * H)[l];
    atomicAdd(&sums[b * H + 2 * l],     hv.x);
    atomicAdd(&sums[b * H + 2 * l + 1], hv.y);
    if (l == 0) atomicAdd(&cnts[b], 1);
}

// ---------------- memory K/V projection ----------------

__global__ void kv_kernel(const float* __restrict__ mb, const float* __restrict__ ipw,
                          const float* __restrict__ ipb,
                          float* __restrict__ kbuf, float* __restrict__ vbuf) {
    __shared__ float rowv[H];
    int m = blockIdx.x, i = threadIdx.x;
    rowv[i] = mb[m * H + i];
    __syncthreads();
    float ak = 0.f, av = 0.f;
    for (int j = 0; j < H; j++) {
        float x = rowv[j];
        ak = fmaf(x, ipw[(size_t)(H + i) * H + j], ak);
        av = fmaf(x, ipw[(size_t)(2 * H + i) * H + j], av);
    }
    kbuf[m * H + i] = ak + ipb[H + i];
    vbuf[m * H + i] = av + ipb[2 * H + i];
}

// ---------------- attention + classifier (one block per graph) ----------------

__launch_bounds__(128)
__global__ void attn_kernel(const float* __restrict__ sums, const int* __restrict__ cnts,
                            const float* __restrict__ kbuf, const float* __restrict__ vbuf,
                            const float* __restrict__ ipw, const float* __restrict__ ipb,
                            const float* __restrict__ out_w, const float* __restrict__ out_b,
                            const float* __restrict__ cw1, const float* __restrict__ cb1,
                            const float* __restrict__ cw2, const float* __restrict__ cb2,
                            float* __restrict__ out) {
    __shared__ float pooled[H], q[H], attn[H], z[2 * H], c1[H], sc[NHEAD * MM];
    int b = blockIdx.x, t = threadIdx.x;
    float cn = (float)max(cnts[b], 1);
    float pv = sums[b * H + t] / cn;
    pooled[t] = pv;
    z[t] = pv;
    __syncthreads();
    // q = pooled @ Wq^T + bq   (Wq = in_proj_w[0:H], torch (out,in) layout)
    float a = 0.f;
    for (int j = 0; j < H; j++) a = fmaf(pooled[j], ipw[(size_t)t * H + j], a);
    q[t] = a + ipb[t];
    __syncthreads();
    // scores[hh][m]
    for (int sidx = t; sidx < NHEAD * MM; sidx += 128) {
        int hh = sidx >> 6, m = sidx & 63;
        float s2 = 0.f;
        for (int d = 0; d < HDIM; d++)
            s2 = fmaf(q[hh * HDIM + d], kbuf[m * H + hh * HDIM + d], s2);
        sc[sidx] = s2 * 0.25f;   // 1/sqrt(16)
    }
    __syncthreads();
    // softmax over m per head (8 serial heads, tiny)
    if (t < NHEAD) {
        float mx = -1e30f;
        for (int m = 0; m < MM; m++) mx = fmaxf(mx, sc[t * MM + m]);
        float ssum = 0.f;
        for (int m = 0; m < MM; m++) { float e = expf(sc[t * MM + m] - mx); sc[t * MM + m] = e; ssum += e; }
        float inv = 1.f / ssum;
        for (int m = 0; m < MM; m++) sc[t * MM + m] *= inv;
    }
    __syncthreads();
    // attn[hh*16+d] = sum_m p[hh][m] * v[m][hh*16+d]
    {
        int hh = t >> 4;
        float a2 = 0.f;
        for (int m = 0; m < MM; m++) a2 = fmaf(sc[hh * MM + m], vbuf[m * H + t], a2);
        attn[t] = a2;
    }
    __syncthreads();
    // mem = attn @ out_w^T + out_b
    float mm = 0.f;
    for (int j = 0; j < H; j++) mm = fmaf(attn[j], out_w[(size_t)t * H + j], mm);
    z[H + t] = mm + out_b[t];
    __syncthreads();
    // c1 = relu(z @ cw1 + cb1)
    float cc = 0.f;
    for (int j = 0; j < 2 * H; j++) cc = fmaf(z[j], cw1[(size_t)j * H + t], cc);
    c1[t] = fmaxf(cc + cb1[t], 0.f);
    __syncthreads();
    if (t < CC) {
        float o = 0.f;
        for (int j = 0; j < H; j++) o = fmaf(c1[j], cw2[j * CC + t], o);
        out[b * CC + t] = o + cb2[t];
    }
}

// ---------------- launch ----------------

extern "C" void kernel_launch(void* const* d_in, const int* in_sizes, int n_in,
                              void* d_out, int out_size, void* d_ws, size_t ws_size,
                              hipStream_t stream) {
    const float* x      = (const float*)d_in[0];
    const int*   eidx   = (const int*)d_in[1];
    const int*   batch  = (const int*)d_in[2];
    const float* w1     = (const float*)d_in[3];
    const float* b1     = (const float*)d_in[4];
    const float* ln_g   = (const float*)d_in[5];
    const float* ln_b   = (const float*)d_in[6];
    const float* gw1    = (const float*)d_in[7];
    const float* gb1    = (const float*)d_in[8];
    const float* gw2    = (const float*)d_in[9];
    const float* gb2    = (const float*)d_in[10];
    const float* gw3    = (const float*)d_in[11];
    const float* gb3    = (const float*)d_in[12];
    const float* memb   = (const float*)d_in[13];
    const float* ipw    = (const float*)d_in[14];
    const float* ipb    = (const float*)d_in[15];
    const float* out_w  = (const float*)d_in[16];
    const float* out_b  = (const float*)d_in[17];
    const float* cw1    = (const float*)d_in[18];
    const float* cb1    = (const float*)d_in[19];
    const float* cw2    = (const float*)d_in[20];
    const float* cb2    = (const float*)d_in[21];

    const int* row = eidx;
    const int* col = eidx + EE;

    char* ws = (char*)d_ws;
    size_t off = 0;
    auto alloc = [&](size_t bytes) -> void* {
        void* p = ws + off;
        off += (bytes + 255) & ~(size_t)255;
        return p;
    };
    float* h_cur  = (float*)alloc((size_t)NN * H * 4);
    float* h_tmp  = (float*)alloc((size_t)NN * H * 4);
    char*  zbeg   = ws + off;
    int*   degcnt = (int*)alloc((size_t)NN * 4);
    float* psums  = (float*)alloc((size_t)BB * H * 4);
    int*   pcnt   = (int*)alloc((size_t)BB * 4);
    size_t zbytes = (size_t)((ws + off) - zbeg);
    float* dis    = (float*)alloc((size_t)NN * 4);
    int*   offs   = (int*)alloc((size_t)NN * 4);
    int*   cursor = (int*)alloc((size_t)NN * 4);
    int*   csr    = (int*)alloc((size_t)EE * 4);
    int*   bsums  = (int*)alloc(256);
    float* kbuf   = (float*)alloc((size_t)MM * H * 4);
    float* vbuf   = (float*)alloc((size_t)MM * H * 4);
    (void)ws_size; (void)in_sizes; (void)n_in; (void)out_size;

    hipMemsetAsync(zbeg, 0, zbytes, stream);

    count_deg<<<(EE + 255) / 256, 256, 0, stream>>>(col, degcnt);
    scan_a<<<NB, 256, 0, stream>>>(degcnt, offs, bsums);
    scan_b<<<1, 64, 0, stream>>>(bsums);
    scan_c<<<(NN + 255) / 256, 256, 0, stream>>>(offs, bsums, degcnt, cursor, dis);
    fill_csr<<<(EE + 255) / 256, 256, 0, stream>>>(row, col, cursor, csr);

    linear_kernel<DIN, true><<<NN / 16, 256, 0, stream>>>(x, w1, b1, ln_g, ln_b, h_cur);

    const float* gws[3] = {gw1, gw2, gw3};
    const float* gbs[3] = {gb1, gb2, gb3};
    for (int layer = 0; layer < 3; layer++) {
        agg_kernel<<<(NN + 3) / 4, 256, 0, stream>>>(h_cur, offs, degcnt, csr, dis, h_tmp);
        linear_kernel<H, false><<<NN / 16, 256, 0, stream>>>(h_tmp, gws[layer], gbs[layer],
                                                             nullptr, nullptr, h_cur);
    }

    pool_kernel<<<(NN + 3) / 4, 256, 0, stream>>>(h_cur, batch, psums, pcnt);
    kv_kernel<<<MM, H, 0, stream>>>(memb, ipw, ipb, kbuf, vbuf);
    attn_kernel<<<BB, H, 0, stream>>>(psums, pcnt, kbuf, vbuf, ipw, ipb, out_w, out_b,
                                      cw1, cb1, cw2, cb2, (float*)d_out);
}

// Round 2
// 554.442 us; speedup vs baseline: 1.3921x; 1.3921x over previous
//
#include <hip/hip_runtime.h>

#define NN 50000
#define EE 800000
#define DIN 256
#define H 128
#define MM 64
#define CC 4
#define BB 128
#define NHEAD 8
#define HDIM 16

#define SCAN_CHUNK 1024
#define NB ((NN + SCAN_CHUNK - 1) / SCAN_CHUNK)   // 49

// ---------------- CSR build ----------------

__global__ void count_deg(const int* __restrict__ col, int* __restrict__ degcnt) {
    int e = blockIdx.x * blockDim.x + threadIdx.x;
    if (e < EE) atomicAdd(&degcnt[col[e]], 1);
}

__global__ void scan_a(const int* __restrict__ degcnt, int* __restrict__ offs,
                       int* __restrict__ bsums) {
    __shared__ int lds[256];
    int t = threadIdx.x;
    int base = blockIdx.x * SCAN_CHUNK + t * 4;
    int v[4]; int s = 0;
    #pragma unroll
    for (int i = 0; i < 4; i++) {
        int ix = base + i;
        v[i] = (ix < NN) ? degcnt[ix] : 0;
        s += v[i];
    }
    lds[t] = s; __syncthreads();
    for (int off = 1; off < 256; off <<= 1) {
        int x = (t >= off) ? lds[t - off] : 0;
        __syncthreads();
        lds[t] += x;
        __syncthreads();
    }
    int incl = lds[t];
    int excl = incl - s;
    if (t == 255) bsums[blockIdx.x] = incl;
    int run = excl;
    #pragma unroll
    for (int i = 0; i < 4; i++) {
        int ix = base + i;
        if (ix < NN) offs[ix] = run;
        run += v[i];
    }
}

__global__ void scan_b(int* __restrict__ bsums) {
    if (threadIdx.x == 0 && blockIdx.x == 0) {
        int run = 0;
        for (int i = 0; i < NB; i++) { int x = bsums[i]; bsums[i] = run; run += x; }
    }
}

__global__ void scan_c(int* __restrict__ offs, const int* __restrict__ bsums,
                       const int* __restrict__ degcnt, int* __restrict__ cursor,
                       float* __restrict__ dis) {
    int v = blockIdx.x * blockDim.x + threadIdx.x;
    if (v < NN) {
        int o = offs[v] + bsums[v / SCAN_CHUNK];
        offs[v] = o;
        cursor[v] = o;
        dis[v] = rsqrtf((float)(degcnt[v] + 1));   // +1 self loop
    }
}

__global__ void fill_csr(const int* __restrict__ row, const int* __restrict__ col,
                         int* __restrict__ cursor, int* __restrict__ csr) {
    int e = blockIdx.x * blockDim.x + threadIdx.x;
    if (e < EE) {
        int u = row[e], v = col[e];
        int p = atomicAdd(&cursor[v], 1);
        csr[p] = u;
    }
}

// ---------------- graph boundaries (batch is sorted) ----------------

__global__ void graph_bounds(const int* __restrict__ batch, int* __restrict__ gstart) {
    int v = blockIdx.x * blockDim.x + threadIdx.x;
    if (v >= NN) return;
    int b = batch[v];
    if (v == 0) {
        for (int g = 0; g <= b; g++) gstart[g] = 0;
    } else {
        int pb = batch[v - 1];
        for (int g = pb + 1; g <= b; g++) gstart[g] = v;
    }
    if (v == NN - 1) {
        for (int g = b + 1; g <= BB; g++) gstart[g] = NN;
    }
}

// ---------------- Linear (+ReLU, optionally +LayerNorm) ----------------

template <int K, bool LN>
__launch_bounds__(256)
__global__ void linear_kernel(const float* __restrict__ A, const float* __restrict__ W,
                              const float* __restrict__ bias,
                              const float* __restrict__ ln_g, const float* __restrict__ ln_b,
                              float* __restrict__ out) {
    constexpr int ROWS = 16, KC = 64;
    __shared__ __align__(16) float w_lds[KC * H];
    __shared__ __align__(16) float x_lds[ROWS * K];
    int t = threadIdx.x;
    int wv = t >> 6, l = t & 63;
    int rowBase = blockIdx.x * ROWS;
    int r0 = wv * 4;
    int c0 = 2 * l;

    {
        const float4* src = reinterpret_cast<const float4*>(A + (size_t)rowBase * K);
        float4* dst = reinterpret_cast<float4*>(x_lds);
        for (int i = t; i < ROWS * K / 4; i += 256) dst[i] = src[i];
    }

    float acc[4][2] = {{0.f,0.f},{0.f,0.f},{0.f,0.f},{0.f,0.f}};

    for (int kc = 0; kc < K; kc += KC) {
        __syncthreads();
        {
            const float4* src = reinterpret_cast<const float4*>(W + (size_t)kc * H);
            float4* dst = reinterpret_cast<float4*>(w_lds);
            for (int i = t; i < KC * H / 4; i += 256) dst[i] = src[i];
        }
        __syncthreads();
        #pragma unroll 8
        for (int k = 0; k < KC; k++) {
            float2 wv2 = *reinterpret_cast<const float2*>(&w_lds[k * H + c0]);
            #pragma unroll
            for (int r = 0; r < 4; r++) {
                float xv = x_lds[(r0 + r) * K + kc + k];
                acc[r][0] = fmaf(xv, wv2.x, acc[r][0]);
                acc[r][1] = fmaf(xv, wv2.y, acc[r][1]);
            }
        }
    }

    float b0 = bias[c0], b1 = bias[c0 + 1];
    if constexpr (LN) {
        float g0 = ln_g[c0], g1 = ln_g[c0 + 1];
        float lb0 = ln_b[c0], lb1 = ln_b[c0 + 1];
        #pragma unroll
        for (int r = 0; r < 4; r++) {
            float v0 = fmaxf(acc[r][0] + b0, 0.f);
            float v1 = fmaxf(acc[r][1] + b1, 0.f);
            float s = v0 + v1, sq = v0 * v0 + v1 * v1;
            #pragma unroll
            for (int m = 1; m < 64; m <<= 1) {
                s  += __shfl_xor(s,  m, 64);
                sq += __shfl_xor(sq, m, 64);
            }
            float mean = s * (1.f / 128.f);
            float var  = sq * (1.f / 128.f) - mean * mean;
            float inv  = rsqrtf(var + 1e-5f);
            float o0 = (v0 - mean) * inv * g0 + lb0;
            float o1 = (v1 - mean) * inv * g1 + lb1;
            int rr = rowBase + r0 + r;
            reinterpret_cast<float2*>(out + (size_t)rr * H)[l] = make_float2(o0, o1);
        }
    } else {
        #pragma unroll
        for (int r = 0; r < 4; r++) {
            float v0 = fmaxf(acc[r][0] + b0, 0.f);
            float v1 = fmaxf(acc[r][1] + b1, 0.f);
            int rr = rowBase + r0 + r;
            reinterpret_cast<float2*>(out + (size_t)rr * H)[l] = make_float2(v0, v1);
        }
    }
}

// ---------------- GCN aggregation ----------------

__launch_bounds__(256)
__global__ void agg_kernel(const float* __restrict__ h, const int* __restrict__ offs,
                           const int* __restrict__ degcnt, const int* __restrict__ csr,
                           const float* __restrict__ dis, float* __restrict__ out) {
    int wv = threadIdx.x >> 6, l = threadIdx.x & 63;
    int v = blockIdx.x * 4 + wv;
    if (v >= NN) return;
    float dv = dis[v];
    float2 self = reinterpret_cast<const float2*>(h + (size_t)v * H)[l];
    float ax = dv * self.x, ay = dv * self.y;
    int beg = offs[v], cnt = degcnt[v];

    int   myu = (l < cnt) ? csr[beg + l] : 0;
    float myd = (l < cnt) ? dis[myu] : 0.f;
    int n0 = cnt < 64 ? cnt : 64;
    for (int i = 0; i < n0; i++) {
        int u = __shfl(myu, i, 64);
        float du = __shfl(myd, i, 64);
        float2 hu = reinterpret_cast<const float2*>(h + (size_t)u * H)[l];
        ax = fmaf(du, hu.x, ax);
        ay = fmaf(du, hu.y, ay);
    }
    for (int i = 64; i < cnt; i++) {
        int u = csr[beg + i];
        float du = dis[u];
        float2 hu = reinterpret_cast<const float2*>(h + (size_t)u * H)[l];
        ax = fmaf(du, hu.x, ax);
        ay = fmaf(du, hu.y, ay);
    }
    reinterpret_cast<float2*>(out + (size_t)v * H)[l] = make_float2(dv * ax, dv * ay);
}

// ---------------- mean pool: chunked segmented sum (batch sorted) ----------------

#define PCHUNK 128

__launch_bounds__(128)
__global__ void pool2_kernel(const float* __restrict__ h, const int* __restrict__ batch,
                             float* __restrict__ psums) {
    __shared__ int bl[PCHUNK];
    int t = threadIdx.x;
    int v0 = blockIdx.x * PCHUNK;
    int v1 = min(v0 + PCHUNK, NN);
    if (v0 >= NN) return;
    if (v0 + t < NN) bl[t] = batch[v0 + t];
    __syncthreads();
    int curb = bl[0];
    float acc = 0.f;
    for (int v = v0; v < v1; v++) {
        int b = bl[v - v0];                 // uniform across block
        if (b != curb) {
            atomicAdd(&psums[curb * H + t], acc);
            acc = 0.f; curb = b;
        }
        acc += h[(size_t)v * H + t];
    }
    atomicAdd(&psums[curb * H + t], acc);
}

// ---------------- memory K/V projection ----------------

__global__ void kv_kernel(const float* __restrict__ mb, const float* __restrict__ ipw,
                          const float* __restrict__ ipb,
                          float* __restrict__ kbuf, float* __restrict__ vbuf) {
    __shared__ float rowv[H];
    int m = blockIdx.x, i = threadIdx.x;
    rowv[i] = mb[m * H + i];
    __syncthreads();
    float ak = 0.f, av = 0.f;
    for (int j = 0; j < H; j++) {
        float x = rowv[j];
        ak = fmaf(x, ipw[(size_t)(H + i) * H + j], ak);
        av = fmaf(x, ipw[(size_t)(2 * H + i) * H + j], av);
    }
    kbuf[m * H + i] = ak + ipb[H + i];
    vbuf[m * H + i] = av + ipb[2 * H + i];
}

// ---------------- attention + classifier (one block per graph) ----------------

__launch_bounds__(128)
__global__ void attn_kernel(const float* __restrict__ psums, const int* __restrict__ gstart,
                            const float* __restrict__ kbuf, const float* __restrict__ vbuf,
                            const float* __restrict__ ipw, const float* __restrict__ ipb,
                            const float* __restrict__ out_w, const float* __restrict__ out_b,
                            const float* __restrict__ cw1, const float* __restrict__ cb1,
                            const float* __restrict__ cw2, const float* __restrict__ cb2,
                            float* __restrict__ out) {
    __shared__ float pooled[H], q[H], attn[H], z[2 * H], c1[H], sc[NHEAD * MM];
    int b = blockIdx.x, t = threadIdx.x;
    float cn = (float)max(gstart[b + 1] - gstart[b], 1);
    float pv = psums[b * H + t] / cn;
    pooled[t] = pv;
    z[t] = pv;
    __syncthreads();
    float a = 0.f;
    for (int j = 0; j < H; j++) a = fmaf(pooled[j], ipw[(size_t)t * H + j], a);
    q[t] = a + ipb[t];
    __syncthreads();
    for (int sidx = t; sidx < NHEAD * MM; sidx += 128) {
        int hh = sidx >> 6, m = sidx & 63;
        float s2 = 0.f;
        for (int d = 0; d < HDIM; d++)
            s2 = fmaf(q[hh * HDIM + d], kbuf[m * H + hh * HDIM + d], s2);
        sc[sidx] = s2 * 0.25f;   // 1/sqrt(16)
    }
    __syncthreads();
    if (t < NHEAD) {
        float mx = -1e30f;
        for (int m = 0; m < MM; m++) mx = fmaxf(mx, sc[t * MM + m]);
        float ssum = 0.f;
        for (int m = 0; m < MM; m++) { float e = expf(sc[t * MM + m] - mx); sc[t * MM + m] = e; ssum += e; }
        float inv = 1.f / ssum;
        for (int m = 0; m < MM; m++) sc[t * MM + m] *= inv;
    }
    __syncthreads();
    {
        int hh = t >> 4;
        float a2 = 0.f;
        for (int m = 0; m < MM; m++) a2 = fmaf(sc[hh * MM + m], vbuf[m * H + t], a2);
        attn[t] = a2;
    }
    __syncthreads();
    float mm = 0.f;
    for (int j = 0; j < H; j++) mm = fmaf(attn[j], out_w[(size_t)t * H + j], mm);
    z[H + t] = mm + out_b[t];
    __syncthreads();
    float cc = 0.f;
    for (int j = 0; j < 2 * H; j++) cc = fmaf(z[j], cw1[(size_t)j * H + t], cc);
    c1[t] = fmaxf(cc + cb1[t], 0.f);
    __syncthreads();
    if (t < CC) {
        float o = 0.f;
        for (int j = 0; j < H; j++) o = fmaf(c1[j], cw2[j * CC + t], o);
        out[b * CC + t] = o + cb2[t];
    }
}

// ---------------- launch ----------------

extern "C" void kernel_launch(void* const* d_in, const int* in_sizes, int n_in,
                              void* d_out, int out_size, void* d_ws, size_t ws_size,
                              hipStream_t stream) {
    const float* x      = (const float*)d_in[0];
    const int*   eidx   = (const int*)d_in[1];
    const int*   batch  = (const int*)d_in[2];
    const float* w1     = (const float*)d_in[3];
    const float* b1     = (const float*)d_in[4];
    const float* ln_g   = (const float*)d_in[5];
    const float* ln_b   = (const float*)d_in[6];
    const float* gw1    = (const float*)d_in[7];
    const float* gb1    = (const float*)d_in[8];
    const float* gw2    = (const float*)d_in[9];
    const float* gb2    = (const float*)d_in[10];
    const float* gw3    = (const float*)d_in[11];
    const float* gb3    = (const float*)d_in[12];
    const float* memb   = (const float*)d_in[13];
    const float* ipw    = (const float*)d_in[14];
    const float* ipb    = (const float*)d_in[15];
    const float* out_w  = (const float*)d_in[16];
    const float* out_b  = (const float*)d_in[17];
    const float* cw1    = (const float*)d_in[18];
    const float* cb1    = (const float*)d_in[19];
    const float* cw2    = (const float*)d_in[20];
    const float* cb2    = (const float*)d_in[21];

    const int* row = eidx;
    const int* col = eidx + EE;

    char* ws = (char*)d_ws;
    size_t off = 0;
    auto alloc = [&](size_t bytes) -> void* {
        void* p = ws + off;
        off += (bytes + 255) & ~(size_t)255;
        return p;
    };
    float* h_cur  = (float*)alloc((size_t)NN * H * 4);
    float* h_tmp  = (float*)alloc((size_t)NN * H * 4);
    char*  zbeg   = ws + off;
    int*   degcnt = (int*)alloc((size_t)NN * 4);
    float* psums  = (float*)alloc((size_t)BB * H * 4);
    size_t zbytes = (size_t)((ws + off) - zbeg);
    float* dis    = (float*)alloc((size_t)NN * 4);
    int*   offs   = (int*)alloc((size_t)NN * 4);
    int*   cursor = (int*)alloc((size_t)NN * 4);
    int*   csr    = (int*)alloc((size_t)EE * 4);
    int*   bsums  = (int*)alloc(256);
    int*   gstart = (int*)alloc((size_t)(BB + 1) * 4);
    float* kbuf   = (float*)alloc((size_t)MM * H * 4);
    float* vbuf   = (float*)alloc((size_t)MM * H * 4);
    (void)ws_size; (void)in_sizes; (void)n_in; (void)out_size;

    hipMemsetAsync(zbeg, 0, zbytes, stream);

    count_deg<<<(EE + 255) / 256, 256, 0, stream>>>(col, degcnt);
    scan_a<<<NB, 256, 0, stream>>>(degcnt, offs, bsums);
    scan_b<<<1, 64, 0, stream>>>(bsums);
    scan_c<<<(NN + 255) / 256, 256, 0, stream>>>(offs, bsums, degcnt, cursor, dis);
    fill_csr<<<(EE + 255) / 256, 256, 0, stream>>>(row, col, cursor, csr);
    graph_bounds<<<(NN + 255) / 256, 256, 0, stream>>>(batch, gstart);

    linear_kernel<DIN, true><<<NN / 16, 256, 0, stream>>>(x, w1, b1, ln_g, ln_b, h_cur);

    const float* gws[3] = {gw1, gw2, gw3};
    const float* gbs[3] = {gb1, gb2, gb3};
    for (int layer = 0; layer < 3; layer++) {
        agg_kernel<<<(NN + 3) / 4, 256, 0, stream>>>(h_cur, offs, degcnt, csr, dis, h_tmp);
        linear_kernel<H, false><<<NN / 16, 256, 0, stream>>>(h_tmp, gws[layer], gbs[layer],
                                                             nullptr, nullptr, h_cur);
    }

    pool2_kernel<<<(NN + PCHUNK - 1) / PCHUNK, PCHUNK, 0, stream>>>(h_cur, batch, psums);
    kv_kernel<<<MM, H, 0, stream>>>(memb, ipw, ipb, kbuf, vbuf);
    attn_kernel<<<BB, H, 0, stream>>>(psums, gstart, kbuf, vbuf, ipw, ipb, out_w, out_b,
                                      cw1, cb1, cw2, cb2, (float*)d_out);
}

// Round 3
// 518.007 us; speedup vs baseline: 1.4900x; 1.0703x over previous
//
#include <hip/hip_runtime.h>

#define NN 50000
#define EE 800000
#define DIN 256
#define H 128
#define MM 64
#define CC 4
#define BB 128
#define NHEAD 8
#define HDIM 16

#define SCAN_CHUNK 1024
#define NB ((NN + SCAN_CHUNK - 1) / SCAN_CHUNK)   // 49

// ---------------- CSR build ----------------

__global__ void count_deg(const int* __restrict__ col, int* __restrict__ degcnt) {
    int e = blockIdx.x * blockDim.x + threadIdx.x;
    if (e < EE) atomicAdd(&degcnt[col[e]], 1);
}

__global__ void scan_a(const int* __restrict__ degcnt, int* __restrict__ offs,
                       int* __restrict__ bsums) {
    __shared__ int lds[256];
    int t = threadIdx.x;
    int base = blockIdx.x * SCAN_CHUNK + t * 4;
    int v[4]; int s = 0;
    #pragma unroll
    for (int i = 0; i < 4; i++) {
        int ix = base + i;
        v[i] = (ix < NN) ? degcnt[ix] : 0;
        s += v[i];
    }
    lds[t] = s; __syncthreads();
    for (int off = 1; off < 256; off <<= 1) {
        int x = (t >= off) ? lds[t - off] : 0;
        __syncthreads();
        lds[t] += x;
        __syncthreads();
    }
    int incl = lds[t];
    int excl = incl - s;
    if (t == 255) bsums[blockIdx.x] = incl;
    int run = excl;
    #pragma unroll
    for (int i = 0; i < 4; i++) {
        int ix = base + i;
        if (ix < NN) offs[ix] = run;
        run += v[i];
    }
}

__global__ void scan_b(int* __restrict__ bsums) {
    if (threadIdx.x == 0 && blockIdx.x == 0) {
        int run = 0;
        for (int i = 0; i < NB; i++) { int x = bsums[i]; bsums[i] = run; run += x; }
    }
}

__global__ void scan_c(int* __restrict__ offs, const int* __restrict__ bsums,
                       const int* __restrict__ degcnt, int* __restrict__ cursor,
                       float* __restrict__ dis) {
    int v = blockIdx.x * blockDim.x + threadIdx.x;
    if (v < NN) {
        int o = offs[v] + bsums[v / SCAN_CHUNK];
        offs[v] = o;
        cursor[v] = o;
        dis[v] = rsqrtf((float)(degcnt[v] + 1));   // +1 self loop
    }
}

__global__ void fill_csr(const int* __restrict__ row, const int* __restrict__ col,
                         int* __restrict__ cursor, int* __restrict__ csr) {
    int e = blockIdx.x * blockDim.x + threadIdx.x;
    if (e < EE) {
        int u = row[e], v = col[e];
        int p = atomicAdd(&cursor[v], 1);
        csr[p] = u;
    }
}

// ---------------- graph boundaries (batch is sorted) ----------------

__global__ void graph_bounds(const int* __restrict__ batch, int* __restrict__ gstart) {
    int v = blockIdx.x * blockDim.x + threadIdx.x;
    if (v >= NN) return;
    int b = batch[v];
    if (v == 0) {
        for (int g = 0; g <= b; g++) gstart[g] = 0;
    } else {
        int pb = batch[v - 1];
        for (int g = pb + 1; g <= b; g++) gstart[g] = v;
    }
    if (v == NN - 1) {
        for (int g = b + 1; g <= BB; g++) gstart[g] = NN;
    }
}

// ---------------- Linear v2: 64-row blocks, 8x4 micro-tile ----------------
// out[r][c] = act( sum_k A[r][k]*W[k][c] + bias[c] ), optional fused LayerNorm.
// 256 threads = 4 waves; rowgroup rg = wv*2 + (l>>5) in [0,8); thread owns
// rows rg*8..rg*8+7, cols (l&31)*4..+4. W and A staged in LDS per 64-K chunk.

template <int K, bool LN>
__launch_bounds__(256)
__global__ void linear_kernel(const float* __restrict__ A, const float* __restrict__ W,
                              const float* __restrict__ bias,
                              const float* __restrict__ ln_g, const float* __restrict__ ln_b,
                              float* __restrict__ out) {
    constexpr int BM = 64, KC = 64;
    __shared__ __align__(16) float w_lds[KC * H];   // 32 KB
    __shared__ __align__(16) float x_lds[BM * KC];  // 16 KB
    int t = threadIdx.x;
    int wv = t >> 6, l = t & 63;
    int rowBase = blockIdx.x * BM;
    int rg = (wv << 1) | (l >> 5);
    int r0 = rg * 8;
    int c0 = (l & 31) * 4;

    float acc[8][4] = {};

    for (int kc = 0; kc < K; kc += KC) {
        __syncthreads();
        {   // stage W chunk [KC][H]
            const float4* src = reinterpret_cast<const float4*>(W + (size_t)kc * H);
            float4* dst = reinterpret_cast<float4*>(w_lds);
            #pragma unroll
            for (int i = 0; i < KC * H / 4 / 256; i++) dst[t + i * 256] = src[t + i * 256];
        }
        {   // stage A chunk [BM][KC]
            #pragma unroll
            for (int ii = 0; ii < BM * KC / 4 / 256; ii++) {
                int i = t + ii * 256;
                int r = i / (KC / 4);
                int cc = i % (KC / 4);
                int gr = rowBase + r;
                float4 v = (gr < NN)
                    ? reinterpret_cast<const float4*>(A + (size_t)gr * K + kc)[cc]
                    : make_float4(0.f, 0.f, 0.f, 0.f);
                reinterpret_cast<float4*>(x_lds + r * KC)[cc] = v;
            }
        }
        __syncthreads();
        #pragma unroll 2
        for (int kk = 0; kk < KC; kk += 4) {
            float4 xr[8];
            #pragma unroll
            for (int r = 0; r < 8; r++)
                xr[r] = *reinterpret_cast<const float4*>(&x_lds[(r0 + r) * KC + kk]);
            #pragma unroll
            for (int kq = 0; kq < 4; kq++) {
                float4 w4 = *reinterpret_cast<const float4*>(&w_lds[(kk + kq) * H + c0]);
                #pragma unroll
                for (int r = 0; r < 8; r++) {
                    float xv = (kq == 0) ? xr[r].x : (kq == 1) ? xr[r].y
                             : (kq == 2) ? xr[r].z : xr[r].w;
                    acc[r][0] = fmaf(xv, w4.x, acc[r][0]);
                    acc[r][1] = fmaf(xv, w4.y, acc[r][1]);
                    acc[r][2] = fmaf(xv, w4.z, acc[r][2]);
                    acc[r][3] = fmaf(xv, w4.w, acc[r][3]);
                }
            }
        }
    }

    float4 b4 = *reinterpret_cast<const float4*>(&bias[c0]);
    if constexpr (LN) {
        float4 g4  = *reinterpret_cast<const float4*>(&ln_g[c0]);
        float4 lb4 = *reinterpret_cast<const float4*>(&ln_b[c0]);
        #pragma unroll
        for (int r = 0; r < 8; r++) {
            int rr = rowBase + r0 + r;
            if (rr < NN) {   // row-uniform within the 32-lane shfl group
                float v0 = fmaxf(acc[r][0] + b4.x, 0.f);
                float v1 = fmaxf(acc[r][1] + b4.y, 0.f);
                float v2 = fmaxf(acc[r][2] + b4.z, 0.f);
                float v3 = fmaxf(acc[r][3] + b4.w, 0.f);
                float s  = v0 + v1 + v2 + v3;
                float sq = v0*v0 + v1*v1 + v2*v2 + v3*v3;
                #pragma unroll
                for (int m = 1; m < 32; m <<= 1) {
                    s  += __shfl_xor(s,  m, 64);
                    sq += __shfl_xor(sq, m, 64);
                }
                float mean = s * (1.f / 128.f);
                float var  = sq * (1.f / 128.f) - mean * mean;
                float inv  = rsqrtf(var + 1e-5f);
                float4 o;
                o.x = (v0 - mean) * inv * g4.x + lb4.x;
                o.y = (v1 - mean) * inv * g4.y + lb4.y;
                o.z = (v2 - mean) * inv * g4.z + lb4.z;
                o.w = (v3 - mean) * inv * g4.w + lb4.w;
                *reinterpret_cast<float4*>(out + (size_t)rr * H + c0) = o;
            }
        }
    } else {
        #pragma unroll
        for (int r = 0; r < 8; r++) {
            int rr = rowBase + r0 + r;
            if (rr < NN) {
                float4 o;
                o.x = fmaxf(acc[r][0] + b4.x, 0.f);
                o.y = fmaxf(acc[r][1] + b4.y, 0.f);
                o.z = fmaxf(acc[r][2] + b4.z, 0.f);
                o.w = fmaxf(acc[r][3] + b4.w, 0.f);
                *reinterpret_cast<float4*>(out + (size_t)rr * H + c0) = o;
            }
        }
    }
}

// ---------------- GCN aggregation ----------------

__launch_bounds__(256)
__global__ void agg_kernel(const float* __restrict__ h, const int* __restrict__ offs,
                           const int* __restrict__ degcnt, const int* __restrict__ csr,
                           const float* __restrict__ dis, float* __restrict__ out) {
    int wv = threadIdx.x >> 6, l = threadIdx.x & 63;
    int v = blockIdx.x * 4 + wv;
    if (v >= NN) return;
    float dv = dis[v];
    float2 self = reinterpret_cast<const float2*>(h + (size_t)v * H)[l];
    float ax = dv * self.x, ay = dv * self.y;
    int beg = offs[v], cnt = degcnt[v];

    int   myu = (l < cnt) ? csr[beg + l] : 0;
    float myd = (l < cnt) ? dis[myu] : 0.f;
    int n0 = cnt < 64 ? cnt : 64;
    for (int i = 0; i < n0; i++) {
        int u = __shfl(myu, i, 64);
        float du = __shfl(myd, i, 64);
        float2 hu = reinterpret_cast<const float2*>(h + (size_t)u * H)[l];
        ax = fmaf(du, hu.x, ax);
        ay = fmaf(du, hu.y, ay);
    }
    for (int i = 64; i < cnt; i++) {
        int u = csr[beg + i];
        float du = dis[u];
        float2 hu = reinterpret_cast<const float2*>(h + (size_t)u * H)[l];
        ax = fmaf(du, hu.x, ax);
        ay = fmaf(du, hu.y, ay);
    }
    reinterpret_cast<float2*>(out + (size_t)v * H)[l] = make_float2(dv * ax, dv * ay);
}

// ---------------- mean pool: chunked segmented sum (batch sorted) ----------------

#define PCHUNK 128

__launch_bounds__(128)
__global__ void pool2_kernel(const float* __restrict__ h, const int* __restrict__ batch,
                             float* __restrict__ psums) {
    __shared__ int bl[PCHUNK];
    int t = threadIdx.x;
    int v0 = blockIdx.x * PCHUNK;
    int v1 = min(v0 + PCHUNK, NN);
    if (v0 >= NN) return;
    if (v0 + t < NN) bl[t] = batch[v0 + t];
    __syncthreads();
    int curb = bl[0];
    float acc = 0.f;
    for (int v = v0; v < v1; v++) {
        int b = bl[v - v0];                 // uniform across block
        if (b != curb) {
            atomicAdd(&psums[curb * H + t], acc);
            acc = 0.f; curb = b;
        }
        acc += h[(size_t)v * H + t];
    }
    atomicAdd(&psums[curb * H + t], acc);
}

// ---------------- memory K/V projection ----------------

__global__ void kv_kernel(const float* __restrict__ mb, const float* __restrict__ ipw,
                          const float* __restrict__ ipb,
                          float* __restrict__ kbuf, float* __restrict__ vbuf) {
    __shared__ float rowv[H];
    int m = blockIdx.x, i = threadIdx.x;
    rowv[i] = mb[m * H + i];
    __syncthreads();
    float ak = 0.f, av = 0.f;
    for (int j = 0; j < H; j++) {
        float x = rowv[j];
        ak = fmaf(x, ipw[(size_t)(H + i) * H + j], ak);
        av = fmaf(x, ipw[(size_t)(2 * H + i) * H + j], av);
    }
    kbuf[m * H + i] = ak + ipb[H + i];
    vbuf[m * H + i] = av + ipb[2 * H + i];
}

// ---------------- attention + classifier (one block per graph) ----------------

__launch_bounds__(128)
__global__ void attn_kernel(const float* __restrict__ psums, const int* __restrict__ gstart,
                            const float* __restrict__ kbuf, const float* __restrict__ vbuf,
                            const float* __restrict__ ipw, const float* __restrict__ ipb,
                            const float* __restrict__ out_w, const float* __restrict__ out_b,
                            const float* __restrict__ cw1, const float* __restrict__ cb1,
                            const float* __restrict__ cw2, const float* __restrict__ cb2,
                            float* __restrict__ out) {
    __shared__ float pooled[H], q[H], attn[H], z[2 * H], c1[H], sc[NHEAD * MM];
    int b = blockIdx.x, t = threadIdx.x;
    float cn = (float)max(gstart[b + 1] - gstart[b], 1);
    float pv = psums[b * H + t] / cn;
    pooled[t] = pv;
    z[t] = pv;
    __syncthreads();
    float a = 0.f;
    for (int j = 0; j < H; j++) a = fmaf(pooled[j], ipw[(size_t)t * H + j], a);
    q[t] = a + ipb[t];
    __syncthreads();
    for (int sidx = t; sidx < NHEAD * MM; sidx += 128) {
        int hh = sidx >> 6, m = sidx & 63;
        float s2 = 0.f;
        for (int d = 0; d < HDIM; d++)
            s2 = fmaf(q[hh * HDIM + d], kbuf[m * H + hh * HDIM + d], s2);
        sc[sidx] = s2 * 0.25f;   // 1/sqrt(16)
    }
    __syncthreads();
    if (t < NHEAD) {
        float mx = -1e30f;
        for (int m = 0; m < MM; m++) mx = fmaxf(mx, sc[t * MM + m]);
        float ssum = 0.f;
        for (int m = 0; m < MM; m++) { float e = expf(sc[t * MM + m] - mx); sc[t * MM + m] = e; ssum += e; }
        float inv = 1.f / ssum;
        for (int m = 0; m < MM; m++) sc[t * MM + m] *= inv;
    }
    __syncthreads();
    {
        int hh = t >> 4;
        float a2 = 0.f;
        for (int m = 0; m < MM; m++) a2 = fmaf(sc[hh * MM + m], vbuf[m * H + t], a2);
        attn[t] = a2;
    }
    __syncthreads();
    float mm = 0.f;
    for (int j = 0; j < H; j++) mm = fmaf(attn[j], out_w[(size_t)t * H + j], mm);
    z[H + t] = mm + out_b[t];
    __syncthreads();
    float cc = 0.f;
    for (int j = 0; j < 2 * H; j++) cc = fmaf(z[j], cw1[(size_t)j * H + t], cc);
    c1[t] = fmaxf(cc + cb1[t], 0.f);
    __syncthreads();
    if (t < CC) {
        float o = 0.f;
        for (int j = 0; j < H; j++) o = fmaf(c1[j], cw2[j * CC + t], o);
        out[b * CC + t] = o + cb2[t];
    }
}

// ---------------- launch ----------------

extern "C" void kernel_launch(void* const* d_in, const int* in_sizes, int n_in,
                              void* d_out, int out_size, void* d_ws, size_t ws_size,
                              hipStream_t stream) {
    const float* x      = (const float*)d_in[0];
    const int*   eidx   = (const int*)d_in[1];
    const int*   batch  = (const int*)d_in[2];
    const float* w1     = (const float*)d_in[3];
    const float* b1     = (const float*)d_in[4];
    const float* ln_g   = (const float*)d_in[5];
    const float* ln_b   = (const float*)d_in[6];
    const float* gw1    = (const float*)d_in[7];
    const float* gb1    = (const float*)d_in[8];
    const float* gw2    = (const float*)d_in[9];
    const float* gb2    = (const float*)d_in[10];
    const float* gw3    = (const float*)d_in[11];
    const float* gb3    = (const float*)d_in[12];
    const float* memb   = (const float*)d_in[13];
    const float* ipw    = (const float*)d_in[14];
    const float* ipb    = (const float*)d_in[15];
    const float* out_w  = (const float*)d_in[16];
    const float* out_b  = (const float*)d_in[17];
    const float* cw1    = (const float*)d_in[18];
    const float* cb1    = (const float*)d_in[19];
    const float* cw2    = (const float*)d_in[20];
    const float* cb2    = (const float*)d_in[21];

    const int* row = eidx;
    const int* col = eidx + EE;

    char* ws = (char*)d_ws;
    size_t off = 0;
    auto alloc = [&](size_t bytes) -> void* {
        void* p = ws + off;
        off += (bytes + 255) & ~(size_t)255;
        return p;
    };
    float* h_cur  = (float*)alloc((size_t)NN * H * 4);
    float* h_tmp  = (float*)alloc((size_t)NN * H * 4);
    char*  zbeg   = ws + off;
    int*   degcnt = (int*)alloc((size_t)NN * 4);
    float* psums  = (float*)alloc((size_t)BB * H * 4);
    size_t zbytes = (size_t)((ws + off) - zbeg);
    float* dis    = (float*)alloc((size_t)NN * 4);
    int*   offs   = (int*)alloc((size_t)NN * 4);
    int*   cursor = (int*)alloc((size_t)NN * 4);
    int*   csr    = (int*)alloc((size_t)EE * 4);
    int*   bsums  = (int*)alloc(256);
    int*   gstart = (int*)alloc((size_t)(BB + 1) * 4);
    float* kbuf   = (float*)alloc((size_t)MM * H * 4);
    float* vbuf   = (float*)alloc((size_t)MM * H * 4);
    (void)ws_size; (void)in_sizes; (void)n_in; (void)out_size;

    hipMemsetAsync(zbeg, 0, zbytes, stream);

    count_deg<<<(EE + 255) / 256, 256, 0, stream>>>(col, degcnt);
    scan_a<<<NB, 256, 0, stream>>>(degcnt, offs, bsums);
    scan_b<<<1, 64, 0, stream>>>(bsums);
    scan_c<<<(NN + 255) / 256, 256, 0, stream>>>(offs, bsums, degcnt, cursor, dis);
    fill_csr<<<(EE + 255) / 256, 256, 0, stream>>>(row, col, cursor, csr);
    graph_bounds<<<(NN + 255) / 256, 256, 0, stream>>>(batch, gstart);

    const int LGRID = (NN + 63) / 64;
    linear_kernel<DIN, true><<<LGRID, 256, 0, stream>>>(x, w1, b1, ln_g, ln_b, h_cur);

    const float* gws[3] = {gw1, gw2, gw3};
    const float* gbs[3] = {gb1, gb2, gb3};
    for (int layer = 0; layer < 3; layer++) {
        agg_kernel<<<(NN + 3) / 4, 256, 0, stream>>>(h_cur, offs, degcnt, csr, dis, h_tmp);
        linear_kernel<H, false><<<LGRID, 256, 0, stream>>>(h_tmp, gws[layer], gbs[layer],
                                                           nullptr, nullptr, h_cur);
    }

    pool2_kernel<<<(NN + PCHUNK - 1) / PCHUNK, PCHUNK, 0, stream>>>(h_cur, batch, psums);
    kv_kernel<<<MM, H, 0, stream>>>(memb, ipw, ipb, kbuf, vbuf);
    attn_kernel<<<BB, H, 0, stream>>>(psums, gstart, kbuf, vbuf, ipw, ipb, out_w, out_b,
                                      cw1, cb1, cw2, cb2, (float*)d_out);
}

// Round 4
// 481.136 us; speedup vs baseline: 1.6042x; 1.0766x over previous
//
#include <hip/hip_runtime.h>

#define NN 50000
#define EE 800000
#define DIN 256
#define H 128
#define MM 64
#define CC 4
#define BB 128
#define NHEAD 8
#define HDIM 16

#define SCAN_CHUNK 1024
#define NB ((NN + SCAN_CHUNK - 1) / SCAN_CHUNK)   // 49

typedef _Float16 f16x8 __attribute__((ext_vector_type(8)));
typedef float f32x4 __attribute__((ext_vector_type(4)));

// ---------------- CSR build ----------------

__global__ void count_deg(const int* __restrict__ col, int* __restrict__ degcnt) {
    int e = blockIdx.x * blockDim.x + threadIdx.x;
    if (e < EE) atomicAdd(&degcnt[col[e]], 1);
}

__global__ void scan_a(const int* __restrict__ degcnt, int* __restrict__ offs,
                       int* __restrict__ bsums) {
    __shared__ int lds[256];
    int t = threadIdx.x;
    int base = blockIdx.x * SCAN_CHUNK + t * 4;
    int v[4]; int s = 0;
    #pragma unroll
    for (int i = 0; i < 4; i++) {
        int ix = base + i;
        v[i] = (ix < NN) ? degcnt[ix] : 0;
        s += v[i];
    }
    lds[t] = s; __syncthreads();
    for (int off = 1; off < 256; off <<= 1) {
        int x = (t >= off) ? lds[t - off] : 0;
        __syncthreads();
        lds[t] += x;
        __syncthreads();
    }
    int incl = lds[t];
    int excl = incl - s;
    if (t == 255) bsums[blockIdx.x] = incl;
    int run = excl;
    #pragma unroll
    for (int i = 0; i < 4; i++) {
        int ix = base + i;
        if (ix < NN) offs[ix] = run;
        run += v[i];
    }
}

__global__ void scan_b(int* __restrict__ bsums) {
    if (threadIdx.x == 0 && blockIdx.x == 0) {
        int run = 0;
        for (int i = 0; i < NB; i++) { int x = bsums[i]; bsums[i] = run; run += x; }
    }
}

__global__ void scan_c(int* __restrict__ offs, const int* __restrict__ bsums,
                       const int* __restrict__ degcnt, int* __restrict__ cursor,
                       float* __restrict__ dis) {
    int v = blockIdx.x * blockDim.x + threadIdx.x;
    if (v < NN) {
        int o = offs[v] + bsums[v / SCAN_CHUNK];
        offs[v] = o;
        cursor[v] = o;
        dis[v] = rsqrtf((float)(degcnt[v] + 1));   // +1 self loop
    }
}

__global__ void fill_csr(const int* __restrict__ row, const int* __restrict__ col,
                         int* __restrict__ cursor, int* __restrict__ csr) {
    int e = blockIdx.x * blockDim.x + threadIdx.x;
    if (e < EE) {
        int u = row[e], v = col[e];
        int p = atomicAdd(&cursor[v], 1);
        csr[p] = u;
    }
}

// ---------------- graph boundaries (batch is sorted) ----------------

__global__ void graph_bounds(const int* __restrict__ batch, int* __restrict__ gstart) {
    int v = blockIdx.x * blockDim.x + threadIdx.x;
    if (v >= NN) return;
    int b = batch[v];
    if (v == 0) {
        for (int g = 0; g <= b; g++) gstart[g] = 0;
    } else {
        int pb = batch[v - 1];
        for (int g = pb + 1; g <= b; g++) gstart[g] = v;
    }
    if (v == NN - 1) {
        for (int g = b + 1; g <= BB; g++) gstart[g] = NN;
    }
}

// ---------------- Linear via fp16-split MFMA ----------------
// out[r][c] = act( sum_k A[r][k]*W[k][c] + bias[c] ), optional fused LayerNorm.
// fp32 emulated as 3 fp16 MFMA passes: xh*wh + xh*wl + xl*wh (fp32 accum).
// Block: 256 thr = 4 waves, 64 rows; wave wv owns rows wv*16..+15, all 128 cols
// as 8 col-tiles of 16. W chunk (128 k's) split+swizzled into LDS so a B-frag
// is one ds_read_b128: lane l holds W[kt*32+(l>>4)*8+j][ct*16+(l&15)].
// A-frags read fp32 global directly, split in-register.
// C/D layout (m89): col=lane&15, row=(lane>>4)*4+reg.

template <int K, bool LN>
__launch_bounds__(256)
__global__ void mfma_linear(const float* __restrict__ A, const float* __restrict__ Wg,
                            const float* __restrict__ bias,
                            const float* __restrict__ ln_g, const float* __restrict__ ln_b,
                            float* __restrict__ out) {
    __shared__ __align__(16) _Float16 wh_lds[4 * 8 * 64 * 8];   // 32 KB
    __shared__ __align__(16) _Float16 wl_lds[4 * 8 * 64 * 8];   // 32 KB
    int t = threadIdx.x;
    int wv = t >> 6, l = t & 63;
    int lm = l & 15, lg = l >> 4;
    int rowBase = blockIdx.x * 64;
    int arow = rowBase + wv * 16 + lm;
    int arc = min(arow, NN - 1);

    f32x4 acc[8];
    #pragma unroll
    for (int ct = 0; ct < 8; ct++) acc[ct] = (f32x4){0.f, 0.f, 0.f, 0.f};

    for (int kc0 = 0; kc0 < K; kc0 += 128) {
        if (kc0) __syncthreads();
        // stage + split W chunk [128][H] into frag-order LDS
        for (int i = t; i < 128 * H; i += 256) {
            int k = i >> 7, c = i & 127;                  // consecutive t -> consecutive c
            float w = Wg[(size_t)(kc0 + k) * H + c];
            _Float16 hh = (_Float16)w;
            _Float16 ll = (_Float16)(w - (float)hh);
            int addr = ((((k >> 5) << 3) | (c >> 4)) * 64
                        + ((((k >> 3) & 3) << 4) | (c & 15))) * 8 + (k & 7);
            wh_lds[addr] = hh;
            wl_lds[addr] = ll;
        }
        __syncthreads();
        #pragma unroll
        for (int kt = 0; kt < 4; kt++) {
            const float* ap = A + (size_t)arc * K + kc0 + kt * 32 + lg * 8;
            float4 a0 = *(const float4*)ap;
            float4 a1 = *(const float4*)(ap + 4);
            float av[8] = {a0.x, a0.y, a0.z, a0.w, a1.x, a1.y, a1.z, a1.w};
            f16x8 ah, al;
            #pragma unroll
            for (int j = 0; j < 8; j++) {
                _Float16 hh = (_Float16)av[j];
                ah[j] = hh;
                al[j] = (_Float16)(av[j] - (float)hh);
            }
            #pragma unroll
            for (int ct = 0; ct < 8; ct++) {
                f16x8 bh = *(const f16x8*)(wh_lds + ((size_t)(kt * 8 + ct) * 64 + l) * 8);
                f16x8 bl = *(const f16x8*)(wl_lds + ((size_t)(kt * 8 + ct) * 64 + l) * 8);
                acc[ct] = __builtin_amdgcn_mfma_f32_16x16x32_f16(ah, bh, acc[ct], 0, 0, 0);
                acc[ct] = __builtin_amdgcn_mfma_f32_16x16x32_f16(ah, bl, acc[ct], 0, 0, 0);
                acc[ct] = __builtin_amdgcn_mfma_f32_16x16x32_f16(al, bh, acc[ct], 0, 0, 0);
            }
        }
    }

    // epilogue: +bias, ReLU, optional LayerNorm, store fp32
    float bv[8], gv[8], lbv[8];
    #pragma unroll
    for (int ct = 0; ct < 8; ct++) {
        int c = ct * 16 + lm;
        bv[ct] = bias[c];
        if constexpr (LN) { gv[ct] = ln_g[c]; lbv[ct] = ln_b[c]; }
    }
    #pragma unroll
    for (int q = 0; q < 4; q++) {
        int rr = rowBase + wv * 16 + lg * 4 + q;
        float vals[8];
        float s = 0.f, sq = 0.f;
        #pragma unroll
        for (int ct = 0; ct < 8; ct++) {
            float v = fmaxf(acc[ct][q] + bv[ct], 0.f);
            vals[ct] = v;
            s += v; sq += v * v;
        }
        if constexpr (LN) {
            // row lives in the 16 lanes sharing lg; masks 1..8 stay in-group
            #pragma unroll
            for (int m = 1; m < 16; m <<= 1) {
                s  += __shfl_xor(s,  m, 64);
                sq += __shfl_xor(sq, m, 64);
            }
            float mean = s * (1.f / 128.f);
            float var  = sq * (1.f / 128.f) - mean * mean;
            float inv  = rsqrtf(var + 1e-5f);
            if (rr < NN) {
                #pragma unroll
                for (int ct = 0; ct < 8; ct++)
                    out[(size_t)rr * H + ct * 16 + lm] = (vals[ct] - mean) * inv * gv[ct] + lbv[ct];
            }
        } else {
            if (rr < NN) {
                #pragma unroll
                for (int ct = 0; ct < 8; ct++)
                    out[(size_t)rr * H + ct * 16 + lm] = vals[ct];
            }
        }
    }
}

// ---------------- GCN aggregation ----------------

__launch_bounds__(256)
__global__ void agg_kernel(const float* __restrict__ h, const int* __restrict__ offs,
                           const int* __restrict__ degcnt, const int* __restrict__ csr,
                           const float* __restrict__ dis, float* __restrict__ out) {
    int wv = threadIdx.x >> 6, l = threadIdx.x & 63;
    int v = blockIdx.x * 4 + wv;
    if (v >= NN) return;
    float dv = dis[v];
    float2 self = reinterpret_cast<const float2*>(h + (size_t)v * H)[l];
    float ax = dv * self.x, ay = dv * self.y;
    int beg = offs[v], cnt = degcnt[v];

    int   myu = (l < cnt) ? csr[beg + l] : 0;
    float myd = (l < cnt) ? dis[myu] : 0.f;
    int n0 = cnt < 64 ? cnt : 64;
    for (int i = 0; i < n0; i++) {
        int u = __shfl(myu, i, 64);
        float du = __shfl(myd, i, 64);
        float2 hu = reinterpret_cast<const float2*>(h + (size_t)u * H)[l];
        ax = fmaf(du, hu.x, ax);
        ay = fmaf(du, hu.y, ay);
    }
    for (int i = 64; i < cnt; i++) {
        int u = csr[beg + i];
        float du = dis[u];
        float2 hu = reinterpret_cast<const float2*>(h + (size_t)u * H)[l];
        ax = fmaf(du, hu.x, ax);
        ay = fmaf(du, hu.y, ay);
    }
    reinterpret_cast<float2*>(out + (size_t)v * H)[l] = make_float2(dv * ax, dv * ay);
}

// ---------------- mean pool: chunked segmented sum (batch sorted) ----------------

#define PCHUNK 128

__launch_bounds__(128)
__global__ void pool2_kernel(const float* __restrict__ h, const int* __restrict__ batch,
                             float* __restrict__ psums) {
    __shared__ int bl[PCHUNK];
    int t = threadIdx.x;
    int v0 = blockIdx.x * PCHUNK;
    int v1 = min(v0 + PCHUNK, NN);
    if (v0 >= NN) return;
    if (v0 + t < NN) bl[t] = batch[v0 + t];
    __syncthreads();
    int curb = bl[0];
    float acc = 0.f;
    for (int v = v0; v < v1; v++) {
        int b = bl[v - v0];                 // uniform across block
        if (b != curb) {
            atomicAdd(&psums[curb * H + t], acc);
            acc = 0.f; curb = b;
        }
        acc += h[(size_t)v * H + t];
    }
    atomicAdd(&psums[curb * H + t], acc);
}

// ---------------- memory K/V projection ----------------

__global__ void kv_kernel(const float* __restrict__ mb, const float* __restrict__ ipw,
                          const float* __restrict__ ipb,
                          float* __restrict__ kbuf, float* __restrict__ vbuf) {
    __shared__ float rowv[H];
    int m = blockIdx.x, i = threadIdx.x;
    rowv[i] = mb[m * H + i];
    __syncthreads();
    float ak = 0.f, av = 0.f;
    for (int j = 0; j < H; j++) {
        float x = rowv[j];
        ak = fmaf(x, ipw[(size_t)(H + i) * H + j], ak);
        av = fmaf(x, ipw[(size_t)(2 * H + i) * H + j], av);
    }
    kbuf[m * H + i] = ak + ipb[H + i];
    vbuf[m * H + i] = av + ipb[2 * H + i];
}

// ---------------- attention + classifier (one block per graph) ----------------

__launch_bounds__(128)
__global__ void attn_kernel(const float* __restrict__ psums, const int* __restrict__ gstart,
                            const float* __restrict__ kbuf, const float* __restrict__ vbuf,
                            const float* __restrict__ ipw, const float* __restrict__ ipb,
                            const float* __restrict__ out_w, const float* __restrict__ out_b,
                            const float* __restrict__ cw1, const float* __restrict__ cb1,
                            const float* __restrict__ cw2, const float* __restrict__ cb2,
                            float* __restrict__ out) {
    __shared__ float pooled[H], q[H], attn[H], z[2 * H], c1[H], sc[NHEAD * MM];
    int b = blockIdx.x, t = threadIdx.x;
    float cn = (float)max(gstart[b + 1] - gstart[b], 1);
    float pv = psums[b * H + t] / cn;
    pooled[t] = pv;
    z[t] = pv;
    __syncthreads();
    float a = 0.f;
    for (int j = 0; j < H; j++) a = fmaf(pooled[j], ipw[(size_t)t * H + j], a);
    q[t] = a + ipb[t];
    __syncthreads();
    for (int sidx = t; sidx < NHEAD * MM; sidx += 128) {
        int hh = sidx >> 6, m = sidx & 63;
        float s2 = 0.f;
        for (int d = 0; d < HDIM; d++)
            s2 = fmaf(q[hh * HDIM + d], kbuf[m * H + hh * HDIM + d], s2);
        sc[sidx] = s2 * 0.25f;   // 1/sqrt(16)
    }
    __syncthreads();
    if (t < NHEAD) {
        float mx = -1e30f;
        for (int m = 0; m < MM; m++) mx = fmaxf(mx, sc[t * MM + m]);
        float ssum = 0.f;
        for (int m = 0; m < MM; m++) { float e = expf(sc[t * MM + m] - mx); sc[t * MM + m] = e; ssum += e; }
        float inv = 1.f / ssum;
        for (int m = 0; m < MM; m++) sc[t * MM + m] *= inv;
    }
    __syncthreads();
    {
        int hh = t >> 4;
        float a2 = 0.f;
        for (int m = 0; m < MM; m++) a2 = fmaf(sc[hh * MM + m], vbuf[m * H + t], a2);
        attn[t] = a2;
    }
    __syncthreads();
    float mm = 0.f;
    for (int j = 0; j < H; j++) mm = fmaf(attn[j], out_w[(size_t)t * H + j], mm);
    z[H + t] = mm + out_b[t];
    __syncthreads();
    float cc = 0.f;
    for (int j = 0; j < 2 * H; j++) cc = fmaf(z[j], cw1[(size_t)j * H + t], cc);
    c1[t] = fmaxf(cc + cb1[t], 0.f);
    __syncthreads();
    if (t < CC) {
        float o = 0.f;
        for (int j = 0; j < H; j++) o = fmaf(c1[j], cw2[j * CC + t], o);
        out[b * CC + t] = o + cb2[t];
    }
}

// ---------------- launch ----------------

extern "C" void kernel_launch(void* const* d_in, const int* in_sizes, int n_in,
                              void* d_out, int out_size, void* d_ws, size_t ws_size,
                              hipStream_t stream) {
    const float* x      = (const float*)d_in[0];
    const int*   eidx   = (const int*)d_in[1];
    const int*   batch  = (const int*)d_in[2];
    const float* w1     = (const float*)d_in[3];
    const float* b1     = (const float*)d_in[4];
    const float* ln_g   = (const float*)d_in[5];
    const float* ln_b   = (const float*)d_in[6];
    const float* gw1    = (const float*)d_in[7];
    const float* gb1    = (const float*)d_in[8];
    const float* gw2    = (const float*)d_in[9];
    const float* gb2    = (const float*)d_in[10];
    const float* gw3    = (const float*)d_in[11];
    const float* gb3    = (const float*)d_in[12];
    const float* memb   = (const float*)d_in[13];
    const float* ipw    = (const float*)d_in[14];
    const float* ipb    = (const float*)d_in[15];
    const float* out_w  = (const float*)d_in[16];
    const float* out_b  = (const float*)d_in[17];
    const float* cw1    = (const float*)d_in[18];
    const float* cb1    = (const float*)d_in[19];
    const float* cw2    = (const float*)d_in[20];
    const float* cb2    = (const float*)d_in[21];

    const int* row = eidx;
    const int* col = eidx + EE;

    char* ws = (char*)d_ws;
    size_t off = 0;
    auto alloc = [&](size_t bytes) -> void* {
        void* p = ws + off;
        off += (bytes + 255) & ~(size_t)255;
        return p;
    };
    float* h_cur  = (float*)alloc((size_t)NN * H * 4);
    float* h_tmp  = (float*)alloc((size_t)NN * H * 4);
    char*  zbeg   = ws + off;
    int*   degcnt = (int*)alloc((size_t)NN * 4);
    float* psums  = (float*)alloc((size_t)BB * H * 4);
    size_t zbytes = (size_t)((ws + off) - zbeg);
    float* dis    = (float*)alloc((size_t)NN * 4);
    int*   offs   = (int*)alloc((size_t)NN * 4);
    int*   cursor = (int*)alloc((size_t)NN * 4);
    int*   csr    = (int*)alloc((size_t)EE * 4);
    int*   bsums  = (int*)alloc(256);
    int*   gstart = (int*)alloc((size_t)(BB + 1) * 4);
    float* kbuf   = (float*)alloc((size_t)MM * H * 4);
    float* vbuf   = (float*)alloc((size_t)MM * H * 4);
    (void)ws_size; (void)in_sizes; (void)n_in; (void)out_size;

    hipMemsetAsync(zbeg, 0, zbytes, stream);

    count_deg<<<(EE + 255) / 256, 256, 0, stream>>>(col, degcnt);
    scan_a<<<NB, 256, 0, stream>>>(degcnt, offs, bsums);
    scan_b<<<1, 64, 0, stream>>>(bsums);
    scan_c<<<(NN + 255) / 256, 256, 0, stream>>>(offs, bsums, degcnt, cursor, dis);
    fill_csr<<<(EE + 255) / 256, 256, 0, stream>>>(row, col, cursor, csr);
    graph_bounds<<<(NN + 255) / 256, 256, 0, stream>>>(batch, gstart);

    const int LGRID = (NN + 63) / 64;   // 782
    mfma_linear<DIN, true><<<LGRID, 256, 0, stream>>>(x, w1, b1, ln_g, ln_b, h_cur);

    const float* gws[3] = {gw1, gw2, gw3};
    const float* gbs[3] = {gb1, gb2, gb3};
    for (int layer = 0; layer < 3; layer++) {
        agg_kernel<<<(NN + 3) / 4, 256, 0, stream>>>(h_cur, offs, degcnt, csr, dis, h_tmp);
        mfma_linear<H, false><<<LGRID, 256, 0, stream>>>(h_tmp, gws[layer], gbs[layer],
                                                         nullptr, nullptr, h_cur);
    }

    pool2_kernel<<<(NN + PCHUNK - 1) / PCHUNK, PCHUNK, 0, stream>>>(h_cur, batch, psums);
    kv_kernel<<<MM, H, 0, stream>>>(memb, ipw, ipb, kbuf, vbuf);
    attn_kernel<<<BB, H, 0, stream>>>(psums, gstart, kbuf, vbuf, ipw, ipb, out_w, out_b,
                                      cw1, cb1, cw2, cb2, (float*)d_out);
}

// Round 5
// 458.963 us; speedup vs baseline: 1.6817x; 1.0483x over previous
//
#include <hip/hip_runtime.h>

#define NN 50000
#define EE 800000
#define DIN 256
#define H 128
#define MM 64
#define CC 4
#define BB 128
#define NHEAD 8
#define HDIM 16

#define SCAN_CHUNK 1024
#define NB ((NN + SCAN_CHUNK - 1) / SCAN_CHUNK)   // 49

typedef _Float16 f16x8 __attribute__((ext_vector_type(8)));
typedef float f32x4 __attribute__((ext_vector_type(4)));

// ---------------- CSR build ----------------

__global__ void count_deg(const int* __restrict__ col, int* __restrict__ degcnt) {
    int e = blockIdx.x * blockDim.x + threadIdx.x;
    if (e < EE) atomicAdd(&degcnt[col[e]], 1);
}

__global__ void scan_a(const int* __restrict__ degcnt, int* __restrict__ offs,
                       int* __restrict__ bsums) {
    __shared__ int lds[256];
    int t = threadIdx.x;
    int base = blockIdx.x * SCAN_CHUNK + t * 4;
    int v[4]; int s = 0;
    #pragma unroll
    for (int i = 0; i < 4; i++) {
        int ix = base + i;
        v[i] = (ix < NN) ? degcnt[ix] : 0;
        s += v[i];
    }
    lds[t] = s; __syncthreads();
    for (int off = 1; off < 256; off <<= 1) {
        int x = (t >= off) ? lds[t - off] : 0;
        __syncthreads();
        lds[t] += x;
        __syncthreads();
    }
    int incl = lds[t];
    int excl = incl - s;
    if (t == 255) bsums[blockIdx.x] = incl;
    int run = excl;
    #pragma unroll
    for (int i = 0; i < 4; i++) {
        int ix = base + i;
        if (ix < NN) offs[ix] = run;
        run += v[i];
    }
}

__global__ void scan_b(int* __restrict__ bsums) {
    if (threadIdx.x == 0 && blockIdx.x == 0) {
        int run = 0;
        for (int i = 0; i < NB; i++) { int x = bsums[i]; bsums[i] = run; run += x; }
    }
}

__global__ void scan_c(int* __restrict__ offs, const int* __restrict__ bsums,
                       const int* __restrict__ degcnt, int* __restrict__ cursor,
                       float* __restrict__ dis) {
    int v = blockIdx.x * blockDim.x + threadIdx.x;
    if (v < NN) {
        int o = offs[v] + bsums[v / SCAN_CHUNK];
        offs[v] = o;
        cursor[v] = o;
        dis[v] = rsqrtf((float)(degcnt[v] + 1));   // +1 self loop
    }
}

__global__ void fill_csr(const int* __restrict__ row, const int* __restrict__ col,
                         int* __restrict__ cursor, int* __restrict__ csr) {
    int e = blockIdx.x * blockDim.x + threadIdx.x;
    if (e < EE) {
        int u = row[e], v = col[e];
        int p = atomicAdd(&cursor[v], 1);
        csr[p] = u;
    }
}

// ---------------- graph boundaries (batch is sorted) ----------------

__global__ void graph_bounds(const int* __restrict__ batch, int* __restrict__ gstart) {
    int v = blockIdx.x * blockDim.x + threadIdx.x;
    if (v >= NN) return;
    int b = batch[v];
    if (v == 0) {
        for (int g = 0; g <= b; g++) gstart[g] = 0;
    } else {
        int pb = batch[v - 1];
        for (int g = pb + 1; g <= b; g++) gstart[g] = v;
    }
    if (v == NN - 1) {
        for (int g = b + 1; g <= BB; g++) gstart[g] = NN;
    }
}

// ---------------- Linear via fp16-split MFMA ----------------
// out[r][c] = act( sum_k A[r][k]*W[k][c] + bias[c] ), optional fused LayerNorm,
// optional row pre-scale by dis[r] (feeds the next GCN aggregation: g = dis .* h).
// fp32 emulated as 3 fp16 MFMA passes: xh*wh + xh*wl + xl*wh (fp32 accum).

template <int K, bool LN, bool SCALE>
__launch_bounds__(256)
__global__ void mfma_linear(const float* __restrict__ A, const float* __restrict__ Wg,
                            const float* __restrict__ bias,
                            const float* __restrict__ ln_g, const float* __restrict__ ln_b,
                            const float* __restrict__ dis,
                            float* __restrict__ out) {
    __shared__ __align__(16) _Float16 wh_lds[4 * 8 * 64 * 8];   // 32 KB
    __shared__ __align__(16) _Float16 wl_lds[4 * 8 * 64 * 8];   // 32 KB
    int t = threadIdx.x;
    int wv = t >> 6, l = t & 63;
    int lm = l & 15, lg = l >> 4;
    int rowBase = blockIdx.x * 64;
    int arow = rowBase + wv * 16 + lm;
    int arc = min(arow, NN - 1);

    f32x4 acc[8];
    #pragma unroll
    for (int ct = 0; ct < 8; ct++) acc[ct] = (f32x4){0.f, 0.f, 0.f, 0.f};

    for (int kc0 = 0; kc0 < K; kc0 += 128) {
        if (kc0) __syncthreads();
        // stage + split W chunk [128][H] into frag-order LDS
        for (int i = t; i < 128 * H; i += 256) {
            int k = i >> 7, c = i & 127;                  // consecutive t -> consecutive c
            float w = Wg[(size_t)(kc0 + k) * H + c];
            _Float16 hh = (_Float16)w;
            _Float16 ll = (_Float16)(w - (float)hh);
            int addr = ((((k >> 5) << 3) | (c >> 4)) * 64
                        + ((((k >> 3) & 3) << 4) | (c & 15))) * 8 + (k & 7);
            wh_lds[addr] = hh;
            wl_lds[addr] = ll;
        }
        __syncthreads();
        #pragma unroll
        for (int kt = 0; kt < 4; kt++) {
            const float* ap = A + (size_t)arc * K + kc0 + kt * 32 + lg * 8;
            float4 a0 = *(const float4*)ap;
            float4 a1 = *(const float4*)(ap + 4);
            float av[8] = {a0.x, a0.y, a0.z, a0.w, a1.x, a1.y, a1.z, a1.w};
            f16x8 ah, al;
            #pragma unroll
            for (int j = 0; j < 8; j++) {
                _Float16 hh = (_Float16)av[j];
                ah[j] = hh;
                al[j] = (_Float16)(av[j] - (float)hh);
            }
            #pragma unroll
            for (int ct = 0; ct < 8; ct++) {
                f16x8 bh = *(const f16x8*)(wh_lds + ((size_t)(kt * 8 + ct) * 64 + l) * 8);
                f16x8 bl = *(const f16x8*)(wl_lds + ((size_t)(kt * 8 + ct) * 64 + l) * 8);
                acc[ct] = __builtin_amdgcn_mfma_f32_16x16x32_f16(ah, bh, acc[ct], 0, 0, 0);
                acc[ct] = __builtin_amdgcn_mfma_f32_16x16x32_f16(ah, bl, acc[ct], 0, 0, 0);
                acc[ct] = __builtin_amdgcn_mfma_f32_16x16x32_f16(al, bh, acc[ct], 0, 0, 0);
            }
        }
    }

    // epilogue: +bias, ReLU, optional LayerNorm, optional dis-scale, store fp32
    float bv[8], gv[8], lbv[8];
    #pragma unroll
    for (int ct = 0; ct < 8; ct++) {
        int c = ct * 16 + lm;
        bv[ct] = bias[c];
        if constexpr (LN) { gv[ct] = ln_g[c]; lbv[ct] = ln_b[c]; }
    }
    #pragma unroll
    for (int q = 0; q < 4; q++) {
        int rr = rowBase + wv * 16 + lg * 4 + q;
        float vals[8];
        float s = 0.f, sq = 0.f;
        #pragma unroll
        for (int ct = 0; ct < 8; ct++) {
            float v = fmaxf(acc[ct][q] + bv[ct], 0.f);
            vals[ct] = v;
            s += v; sq += v * v;
        }
        if constexpr (LN) {
            // row lives in the 16 lanes sharing lg; masks 1..8 stay in-group
            #pragma unroll
            for (int m = 1; m < 16; m <<= 1) {
                s  += __shfl_xor(s,  m, 64);
                sq += __shfl_xor(sq, m, 64);
            }
            float mean = s * (1.f / 128.f);
            float var  = sq * (1.f / 128.f) - mean * mean;
            float inv  = rsqrtf(var + 1e-5f);
            if (rr < NN) {
                float sc = SCALE ? dis[rr] : 1.f;
                #pragma unroll
                for (int ct = 0; ct < 8; ct++)
                    out[(size_t)rr * H + ct * 16 + lm] =
                        ((vals[ct] - mean) * inv * gv[ct] + lbv[ct]) * sc;
            }
        } else {
            if (rr < NN) {
                float sc = SCALE ? dis[rr] : 1.f;
                #pragma unroll
                for (int ct = 0; ct < 8; ct++)
                    out[(size_t)rr * H + ct * 16 + lm] = vals[ct] * sc;
            }
        }
    }
}

// ---------------- GCN aggregation v2 ----------------
// Input g = dis .* h (pre-scaled by the producing linear). Output
// out[v] = dis[v] * ( g[v] + sum_{u in N(v)} g[u] ).
// 32-lane group per node (8 nodes / 256-block), float4 per lane (16B), inner
// loop unrolled x4 -> 4 independent 512B row-loads in flight per group.

__launch_bounds__(256)
__global__ void agg_kernel(const float* __restrict__ g, const int* __restrict__ offs,
                           const int* __restrict__ degcnt, const int* __restrict__ csr,
                           const float* __restrict__ dis, float* __restrict__ out) {
    int grp = threadIdx.x >> 5;        // 0..7
    int l = threadIdx.x & 31;
    int v = blockIdx.x * 8 + grp;
    if (v >= NN) return;
    const float4* __restrict__ G = reinterpret_cast<const float4*>(g);   // 32 float4 per row
    float dv = dis[v];
    float4 acc = G[(size_t)v * 32 + l];          // self term g[v]
    int beg = offs[v], cnt = degcnt[v];

    int myu = (l < cnt) ? csr[beg + l] : 0;
    int n0 = min(cnt, 32);
    int i = 0;
    for (; i + 4 <= n0; i += 4) {
        int u0 = __shfl(myu, i,     32);
        int u1 = __shfl(myu, i + 1, 32);
        int u2 = __shfl(myu, i + 2, 32);
        int u3 = __shfl(myu, i + 3, 32);
        float4 a = G[(size_t)u0 * 32 + l];
        float4 b = G[(size_t)u1 * 32 + l];
        float4 c = G[(size_t)u2 * 32 + l];
        float4 d = G[(size_t)u3 * 32 + l];
        acc.x += (a.x + b.x) + (c.x + d.x);
        acc.y += (a.y + b.y) + (c.y + d.y);
        acc.z += (a.z + b.z) + (c.z + d.z);
        acc.w += (a.w + b.w) + (c.w + d.w);
    }
    for (; i < n0; i++) {
        int u = __shfl(myu, i, 32);
        float4 a = G[(size_t)u * 32 + l];
        acc.x += a.x; acc.y += a.y; acc.z += a.z; acc.w += a.w;
    }
    // neighbors beyond 32 (rare): direct index loads, still unrolled x4
    for (; i + 4 <= cnt; i += 4) {
        int u0 = csr[beg + i], u1 = csr[beg + i + 1];
        int u2 = csr[beg + i + 2], u3 = csr[beg + i + 3];
        float4 a = G[(size_t)u0 * 32 + l];
        float4 b = G[(size_t)u1 * 32 + l];
        float4 c = G[(size_t)u2 * 32 + l];
        float4 d = G[(size_t)u3 * 32 + l];
        acc.x += (a.x + b.x) + (c.x + d.x);
        acc.y += (a.y + b.y) + (c.y + d.y);
        acc.z += (a.z + b.z) + (c.z + d.z);
        acc.w += (a.w + b.w) + (c.w + d.w);
    }
    for (; i < cnt; i++) {
        int u = csr[beg + i];
        float4 a = G[(size_t)u * 32 + l];
        acc.x += a.x; acc.y += a.y; acc.z += a.z; acc.w += a.w;
    }
    float4 o;
    o.x = dv * acc.x; o.y = dv * acc.y; o.z = dv * acc.z; o.w = dv * acc.w;
    reinterpret_cast<float4*>(out)[(size_t)v * 32 + l] = o;
}

// ---------------- mean pool: chunked segmented sum (batch sorted) ----------------

#define PCHUNK 128

__launch_bounds__(128)
__global__ void pool2_kernel(const float* __restrict__ h, const int* __restrict__ batch,
                             float* __restrict__ psums) {
    __shared__ int bl[PCHUNK];
    int t = threadIdx.x;
    int v0 = blockIdx.x * PCHUNK;
    int v1 = min(v0 + PCHUNK, NN);
    if (v0 >= NN) return;
    if (v0 + t < NN) bl[t] = batch[v0 + t];
    __syncthreads();
    int curb = bl[0];
    float acc = 0.f;
    for (int v = v0; v < v1; v++) {
        int b = bl[v - v0];                 // uniform across block
        if (b != curb) {
            atomicAdd(&psums[curb * H + t], acc);
            acc = 0.f; curb = b;
        }
        acc += h[(size_t)v * H + t];
    }
    atomicAdd(&psums[curb * H + t], acc);
}

// ---------------- memory K/V projection ----------------

__global__ void kv_kernel(const float* __restrict__ mb, const float* __restrict__ ipw,
                          const float* __restrict__ ipb,
                          float* __restrict__ kbuf, float* __restrict__ vbuf) {
    __shared__ float rowv[H];
    int m = blockIdx.x, i = threadIdx.x;
    rowv[i] = mb[m * H + i];
    __syncthreads();
    float ak = 0.f, av = 0.f;
    for (int j = 0; j < H; j++) {
        float x = rowv[j];
        ak = fmaf(x, ipw[(size_t)(H + i) * H + j], ak);
        av = fmaf(x, ipw[(size_t)(2 * H + i) * H + j], av);
    }
    kbuf[m * H + i] = ak + ipb[H + i];
    vbuf[m * H + i] = av + ipb[2 * H + i];
}

// ---------------- attention + classifier (one block per graph) ----------------

__launch_bounds__(128)
__global__ void attn_kernel(const float* __restrict__ psums, const int* __restrict__ gstart,
                            const float* __restrict__ kbuf, const float* __restrict__ vbuf,
                            const float* __restrict__ ipw, const float* __restrict__ ipb,
                            const float* __restrict__ out_w, const float* __restrict__ out_b,
                            const float* __restrict__ cw1, const float* __restrict__ cb1,
                            const float* __restrict__ cw2, const float* __restrict__ cb2,
                            float* __restrict__ out) {
    __shared__ float pooled[H], q[H], attn[H], z[2 * H], c1[H], sc[NHEAD * MM];
    int b = blockIdx.x, t = threadIdx.x;
    float cn = (float)max(gstart[b + 1] - gstart[b], 1);
    float pv = psums[b * H + t] / cn;
    pooled[t] = pv;
    z[t] = pv;
    __syncthreads();
    float a = 0.f;
    for (int j = 0; j < H; j++) a = fmaf(pooled[j], ipw[(size_t)t * H + j], a);
    q[t] = a + ipb[t];
    __syncthreads();
    for (int sidx = t; sidx < NHEAD * MM; sidx += 128) {
        int hh = sidx >> 6, m = sidx & 63;
        float s2 = 0.f;
        for (int d = 0; d < HDIM; d++)
            s2 = fmaf(q[hh * HDIM + d], kbuf[m * H + hh * HDIM + d], s2);
        sc[sidx] = s2 * 0.25f;   // 1/sqrt(16)
    }
    __syncthreads();
    if (t < NHEAD) {
        float mx = -1e30f;
        for (int m = 0; m < MM; m++) mx = fmaxf(mx, sc[t * MM + m]);
        float ssum = 0.f;
        for (int m = 0; m < MM; m++) { float e = expf(sc[t * MM + m] - mx); sc[t * MM + m] = e; ssum += e; }
        float inv = 1.f / ssum;
        for (int m = 0; m < MM; m++) sc[t * MM + m] *= inv;
    }
    __syncthreads();
    {
        int hh = t >> 4;
        float a2 = 0.f;
        for (int m = 0; m < MM; m++) a2 = fmaf(sc[hh * MM + m], vbuf[m * H + t], a2);
        attn[t] = a2;
    }
    __syncthreads();
    float mm = 0.f;
    for (int j = 0; j < H; j++) mm = fmaf(attn[j], out_w[(size_t)t * H + j], mm);
    z[H + t] = mm + out_b[t];
    __syncthreads();
    float cc = 0.f;
    for (int j = 0; j < 2 * H; j++) cc = fmaf(z[j], cw1[(size_t)j * H + t], cc);
    c1[t] = fmaxf(cc + cb1[t], 0.f);
    __syncthreads();
    if (t < CC) {
        float o = 0.f;
        for (int j = 0; j < H; j++) o = fmaf(c1[j], cw2[j * CC + t], o);
        out[b * CC + t] = o + cb2[t];
    }
}

// ---------------- launch ----------------

extern "C" void kernel_launch(void* const* d_in, const int* in_sizes, int n_in,
                              void* d_out, int out_size, void* d_ws, size_t ws_size,
                              hipStream_t stream) {
    const float* x      = (const float*)d_in[0];
    const int*   eidx   = (const int*)d_in[1];
    const int*   batch  = (const int*)d_in[2];
    const float* w1     = (const float*)d_in[3];
    const float* b1     = (const float*)d_in[4];
    const float* ln_g   = (const float*)d_in[5];
    const float* ln_b   = (const float*)d_in[6];
    const float* gw1    = (const float*)d_in[7];
    const float* gb1    = (const float*)d_in[8];
    const float* gw2    = (const float*)d_in[9];
    const float* gb2    = (const float*)d_in[10];
    const float* gw3    = (const float*)d_in[11];
    const float* gb3    = (const float*)d_in[12];
    const float* memb   = (const float*)d_in[13];
    const float* ipw    = (const float*)d_in[14];
    const float* ipb    = (const float*)d_in[15];
    const float* out_w  = (const float*)d_in[16];
    const float* out_b  = (const float*)d_in[17];
    const float* cw1    = (const float*)d_in[18];
    const float* cb1    = (const float*)d_in[19];
    const float* cw2    = (const float*)d_in[20];
    const float* cb2    = (const float*)d_in[21];

    const int* row = eidx;
    const int* col = eidx + EE;

    char* ws = (char*)d_ws;
    size_t off = 0;
    auto alloc = [&](size_t bytes) -> void* {
        void* p = ws + off;
        off += (bytes + 255) & ~(size_t)255;
        return p;
    };
    float* h_cur  = (float*)alloc((size_t)NN * H * 4);
    float* h_tmp  = (float*)alloc((size_t)NN * H * 4);
    char*  zbeg   = ws + off;
    int*   degcnt = (int*)alloc((size_t)NN * 4);
    float* psums  = (float*)alloc((size_t)BB * H * 4);
    size_t zbytes = (size_t)((ws + off) - zbeg);
    float* dis    = (float*)alloc((size_t)NN * 4);
    int*   offs   = (int*)alloc((size_t)NN * 4);
    int*   cursor = (int*)alloc((size_t)NN * 4);
    int*   csr    = (int*)alloc((size_t)EE * 4);
    int*   bsums  = (int*)alloc(256);
    int*   gstart = (int*)alloc((size_t)(BB + 1) * 4);
    float* kbuf   = (float*)alloc((size_t)MM * H * 4);
    float* vbuf   = (float*)alloc((size_t)MM * H * 4);
    (void)ws_size; (void)in_sizes; (void)n_in; (void)out_size;

    hipMemsetAsync(zbeg, 0, zbytes, stream);

    count_deg<<<(EE + 255) / 256, 256, 0, stream>>>(col, degcnt);
    scan_a<<<NB, 256, 0, stream>>>(degcnt, offs, bsums);
    scan_b<<<1, 64, 0, stream>>>(bsums);
    scan_c<<<(NN + 255) / 256, 256, 0, stream>>>(offs, bsums, degcnt, cursor, dis);
    fill_csr<<<(EE + 255) / 256, 256, 0, stream>>>(row, col, cursor, csr);
    graph_bounds<<<(NN + 255) / 256, 256, 0, stream>>>(batch, gstart);

    const int LGRID = (NN + 63) / 64;   // 782
    const int AGRID = (NN + 7) / 8;     // 6250

    // feature transform; output pre-scaled by dis (feeds agg layer 1)
    mfma_linear<DIN, true, true><<<LGRID, 256, 0, stream>>>(x, w1, b1, ln_g, ln_b, dis, h_cur);

    // GCN layer 1
    agg_kernel<<<AGRID, 256, 0, stream>>>(h_cur, offs, degcnt, csr, dis, h_tmp);
    mfma_linear<H, false, true><<<LGRID, 256, 0, stream>>>(h_tmp, gw1, gb1, nullptr, nullptr, dis, h_cur);
    // GCN layer 2
    agg_kernel<<<AGRID, 256, 0, stream>>>(h_cur, offs, degcnt, csr, dis, h_tmp);
    mfma_linear<H, false, true><<<LGRID, 256, 0, stream>>>(h_tmp, gw2, gb2, nullptr, nullptr, dis, h_cur);
    // GCN layer 3 (unscaled output -> pool)
    agg_kernel<<<AGRID, 256, 0, stream>>>(h_cur, offs, degcnt, csr, dis, h_tmp);
    mfma_linear<H, false, false><<<LGRID, 256, 0, stream>>>(h_tmp, gw3, gb3, nullptr, nullptr, dis, h_cur);

    pool2_kernel<<<(NN + PCHUNK - 1) / PCHUNK, PCHUNK, 0, stream>>>(h_cur, batch, psums);
    kv_kernel<<<MM, H, 0, stream>>>(memb, ipw, ipb, kbuf, vbuf);
    attn_kernel<<<BB, H, 0, stream>>>(psums, gstart, kbuf, vbuf, ipw, ipb, out_w, out_b,
                                      cw1, cb1, cw2, cb2, (float*)d_out);
}

// Round 6
// 425.551 us; speedup vs baseline: 1.8138x; 1.0785x over previous
//
#include <hip/hip_runtime.h>

#define NN 50000
#define EE 800000
#define DIN 256
#define H 128
#define MM 64
#define CC 4
#define BB 128
#define NHEAD 8
#define HDIM 16

#define SCAN_CHUNK 1024
#define NB ((NN + SCAN_CHUNK - 1) / SCAN_CHUNK)   // 49

typedef _Float16 f16x8 __attribute__((ext_vector_type(8)));
typedef float f32x4 __attribute__((ext_vector_type(4)));

// ---------------- CSR build ----------------

__global__ void count_deg(const int* __restrict__ col, int* __restrict__ degcnt) {
    int e = blockIdx.x * blockDim.x + threadIdx.x;
    if (e < EE) atomicAdd(&degcnt[col[e]], 1);
}

__global__ void scan_a(const int* __restrict__ degcnt, int* __restrict__ offs,
                       int* __restrict__ bsums) {
    __shared__ int lds[256];
    int t = threadIdx.x;
    int base = blockIdx.x * SCAN_CHUNK + t * 4;
    int v[4]; int s = 0;
    #pragma unroll
    for (int i = 0; i < 4; i++) {
        int ix = base + i;
        v[i] = (ix < NN) ? degcnt[ix] : 0;
        s += v[i];
    }
    lds[t] = s; __syncthreads();
    for (int off = 1; off < 256; off <<= 1) {
        int x = (t >= off) ? lds[t - off] : 0;
        __syncthreads();
        lds[t] += x;
        __syncthreads();
    }
    int incl = lds[t];
    int excl = incl - s;
    if (t == 255) bsums[blockIdx.x] = incl;
    int run = excl;
    #pragma unroll
    for (int i = 0; i < 4; i++) {
        int ix = base + i;
        if (ix < NN) offs[ix] = run;
        run += v[i];
    }
}

__global__ void scan_b(int* __restrict__ bsums) {
    if (threadIdx.x == 0 && blockIdx.x == 0) {
        int run = 0;
        for (int i = 0; i < NB; i++) { int x = bsums[i]; bsums[i] = run; run += x; }
    }
}

__global__ void scan_c(int* __restrict__ offs, const int* __restrict__ bsums,
                       const int* __restrict__ degcnt, int* __restrict__ cursor,
                       float* __restrict__ dis) {
    int v = blockIdx.x * blockDim.x + threadIdx.x;
    if (v < NN) {
        int o = offs[v] + bsums[v / SCAN_CHUNK];
        offs[v] = o;
        cursor[v] = o;
        dis[v] = rsqrtf((float)(degcnt[v] + 1));   // +1 self loop
    }
}

__global__ void fill_csr(const int* __restrict__ row, const int* __restrict__ col,
                         int* __restrict__ cursor, int* __restrict__ csr) {
    int e = blockIdx.x * blockDim.x + threadIdx.x;
    if (e < EE) {
        int u = row[e], v = col[e];
        int p = atomicAdd(&cursor[v], 1);
        csr[p] = u;
    }
}

// ---------------- graph boundaries (batch is sorted) ----------------

__global__ void graph_bounds(const int* __restrict__ batch, int* __restrict__ gstart) {
    int v = blockIdx.x * blockDim.x + threadIdx.x;
    if (v >= NN) return;
    int b = batch[v];
    if (v == 0) {
        for (int g = 0; g <= b; g++) gstart[g] = 0;
    } else {
        int pb = batch[v - 1];
        for (int g = pb + 1; g <= b; g++) gstart[g] = v;
    }
    if (v == NN - 1) {
        for (int g = b + 1; g <= BB; g++) gstart[g] = NN;
    }
}

// ---------------- W split to frag-ordered fp16 hi/lo (once per launch) ----------------
// Layout: frag f = kt*8+ct; hi at ((f*64+l)*8+j), lo at offset KT*8*64*8 halfwords.
// Frag element (l,j) = W[kt*32+(l>>4)*8+j][ct*16+(l&15)].

__global__ void wsplit(const float* __restrict__ Wg, _Float16* __restrict__ outw, int KT) {
    int f = blockIdx.x;           // 0..KT*8-1
    int l = threadIdx.x;          // 0..63
    int kt = f >> 3, ct = f & 7;
    int k0 = kt * 32 + (l >> 4) * 8;
    int c = ct * 16 + (l & 15);
    f16x8 hi, lo;
    #pragma unroll
    for (int j = 0; j < 8; j++) {
        float w = Wg[(size_t)(k0 + j) * H + c];
        _Float16 hh = (_Float16)w;
        hi[j] = hh;
        lo[j] = (_Float16)(w - (float)hh);
    }
    *reinterpret_cast<f16x8*>(outw + ((size_t)f * 64 + l) * 8) = hi;
    *reinterpret_cast<f16x8*>(outw + ((size_t)KT * 8 * 64 * 8) + ((size_t)f * 64 + l) * 8) = lo;
}

// ---------------- Linear via fp16-split MFMA (no LDS; W-frags from global/L2) ----------
// out[r][c] = act( sum_k A[r][k]*W[k][c] + bias[c] ), optional fused LayerNorm,
// optional row pre-scale by dis[r].  3 fp16 passes: xh*wh + xh*wl + xl*wh.

template <int K, bool LN, bool SCALE>
__launch_bounds__(256)
__global__ void mfma_linear(const float* __restrict__ A, const _Float16* __restrict__ Wf,
                            const float* __restrict__ bias,
                            const float* __restrict__ ln_g, const float* __restrict__ ln_b,
                            const float* __restrict__ dis,
                            float* __restrict__ out) {
    constexpr int KT = K / 32;
    int t = threadIdx.x;
    int wv = t >> 6, l = t & 63;
    int lm = l & 15, lg = l >> 4;
    int rowBase = blockIdx.x * 64;
    int arow = rowBase + wv * 16 + lm;
    int arc = min(arow, NN - 1);
    const f16x8* __restrict__ Bh = reinterpret_cast<const f16x8*>(Wf);
    const f16x8* __restrict__ Bl = Bh + KT * 8 * 64;

    f32x4 acc[8];
    #pragma unroll
    for (int ct = 0; ct < 8; ct++) acc[ct] = (f32x4){0.f, 0.f, 0.f, 0.f};

    #pragma unroll
    for (int kt = 0; kt < KT; kt++) {
        const float* ap = A + (size_t)arc * K + kt * 32 + lg * 8;
        float4 a0 = *(const float4*)ap;
        float4 a1 = *(const float4*)(ap + 4);
        float av[8] = {a0.x, a0.y, a0.z, a0.w, a1.x, a1.y, a1.z, a1.w};
        f16x8 ah, al;
        #pragma unroll
        for (int j = 0; j < 8; j++) {
            _Float16 hh = (_Float16)av[j];
            ah[j] = hh;
            al[j] = (_Float16)(av[j] - (float)hh);
        }
        #pragma unroll
        for (int ct = 0; ct < 8; ct++) {
            f16x8 bh = Bh[(size_t)(kt * 8 + ct) * 64 + l];
            f16x8 bl = Bl[(size_t)(kt * 8 + ct) * 64 + l];
            acc[ct] = __builtin_amdgcn_mfma_f32_16x16x32_f16(ah, bh, acc[ct], 0, 0, 0);
            acc[ct] = __builtin_amdgcn_mfma_f32_16x16x32_f16(ah, bl, acc[ct], 0, 0, 0);
            acc[ct] = __builtin_amdgcn_mfma_f32_16x16x32_f16(al, bh, acc[ct], 0, 0, 0);
        }
    }

    // epilogue: +bias, ReLU, optional LayerNorm, optional dis-scale, store fp32
    float bv[8], gv[8], lbv[8];
    #pragma unroll
    for (int ct = 0; ct < 8; ct++) {
        int c = ct * 16 + lm;
        bv[ct] = bias[c];
        if constexpr (LN) { gv[ct] = ln_g[c]; lbv[ct] = ln_b[c]; }
    }
    #pragma unroll
    for (int q = 0; q < 4; q++) {
        int rr = rowBase + wv * 16 + lg * 4 + q;
        float vals[8];
        float s = 0.f, sq = 0.f;
        #pragma unroll
        for (int ct = 0; ct < 8; ct++) {
            float v = fmaxf(acc[ct][q] + bv[ct], 0.f);
            vals[ct] = v;
            s += v; sq += v * v;
        }
        if constexpr (LN) {
            // row lives in the 16 lanes sharing lg; masks 1..8 stay in-group
            #pragma unroll
            for (int m = 1; m < 16; m <<= 1) {
                s  += __shfl_xor(s,  m, 64);
                sq += __shfl_xor(sq, m, 64);
            }
            float mean = s * (1.f / 128.f);
            float var  = sq * (1.f / 128.f) - mean * mean;
            float inv  = rsqrtf(var + 1e-5f);
            if (rr < NN) {
                float sc = SCALE ? dis[rr] : 1.f;
                #pragma unroll
                for (int ct = 0; ct < 8; ct++)
                    out[(size_t)rr * H + ct * 16 + lm] =
                        ((vals[ct] - mean) * inv * gv[ct] + lbv[ct]) * sc;
            }
        } else {
            if (rr < NN) {
                float sc = SCALE ? dis[rr] : 1.f;
                #pragma unroll
                for (int ct = 0; ct < 8; ct++)
                    out[(size_t)rr * H + ct * 16 + lm] = vals[ct] * sc;
            }
        }
    }
}

// ---------------- GCN aggregation v3 ----------------
// Input g = dis .* h. out[v] = dis[v] * ( g[v] + sum_{u in N(v)} g[u] ).
// 32-lane group per node (8 nodes/block). Indices staged in LDS padded with v
// (compensated), 8-wide unrolled gather with a static float4 array -> 8
// independent 512B row loads in flight per group.

__launch_bounds__(256)
__global__ void agg_kernel(const float* __restrict__ g, const int* __restrict__ offs,
                           const int* __restrict__ degcnt, const int* __restrict__ csr,
                           const float* __restrict__ dis, float* __restrict__ out) {
    __shared__ int idx[8][64];
    int grp = threadIdx.x >> 5;        // 0..7
    int l = threadIdx.x & 31;
    int v = blockIdx.x * 8 + grp;
    bool valid = v < NN;
    int beg = 0, cnt = 0;
    if (valid) {
        beg = offs[v]; cnt = degcnt[v];
        idx[grp][l]      = (l      < cnt) ? csr[beg + l]      : v;
        idx[grp][l + 32] = (l + 32 < cnt) ? csr[beg + l + 32] : v;
    }
    __syncthreads();
    if (!valid) return;

    const float4* __restrict__ G = reinterpret_cast<const float4*>(g);  // 32 float4/row
    float dv = dis[v];
    float4 gv = G[(size_t)v * 32 + l];
    float4 acc = gv;                       // self term
    int n0 = min(cnt, 64);
    int m0 = (n0 + 7) & ~7;                // padded trip count

    for (int i = 0; i < m0; i += 8) {
        float4 tv[8];
        #pragma unroll
        for (int jj = 0; jj < 8; jj++)
            tv[jj] = G[(size_t)idx[grp][i + jj] * 32 + l];
        #pragma unroll
        for (int jj = 0; jj < 8; jj++) {
            acc.x += tv[jj].x; acc.y += tv[jj].y;
            acc.z += tv[jj].z; acc.w += tv[jj].w;
        }
    }
    float pad = (float)(m0 - n0);          // remove padded copies of g[v]
    acc.x -= pad * gv.x; acc.y -= pad * gv.y;
    acc.z -= pad * gv.z; acc.w -= pad * gv.w;

    for (int i = 64; i < cnt; i++) {       // degree > 64 tail (essentially never)
        float4 a = G[(size_t)csr[beg + i] * 32 + l];
        acc.x += a.x; acc.y += a.y; acc.z += a.z; acc.w += a.w;
    }
    float4 o;
    o.x = dv * acc.x; o.y = dv * acc.y; o.z = dv * acc.z; o.w = dv * acc.w;
    reinterpret_cast<float4*>(out)[(size_t)v * 32 + l] = o;
}

// ---------------- mean pool: chunked segmented sum (batch sorted) ----------------

#define PCHUNK 128

__launch_bounds__(128)
__global__ void pool2_kernel(const float* __restrict__ h, const int* __restrict__ batch,
                             float* __restrict__ psums) {
    __shared__ int bl[PCHUNK];
    int t = threadIdx.x;
    int v0 = blockIdx.x * PCHUNK;
    int v1 = min(v0 + PCHUNK, NN);
    if (v0 >= NN) return;
    if (v0 + t < NN) bl[t] = batch[v0 + t];
    __syncthreads();
    int curb = bl[0];
    float acc = 0.f;
    for (int v = v0; v < v1; v++) {
        int b = bl[v - v0];                 // uniform across block
        if (b != curb) {
            atomicAdd(&psums[curb * H + t], acc);
            acc = 0.f; curb = b;
        }
        acc += h[(size_t)v * H + t];
    }
    atomicAdd(&psums[curb * H + t], acc);
}

// ---------------- memory K/V projection ----------------

__global__ void kv_kernel(const float* __restrict__ mb, const float* __restrict__ ipw,
                          const float* __restrict__ ipb,
                          float* __restrict__ kbuf, float* __restrict__ vbuf) {
    __shared__ float rowv[H];
    int m = blockIdx.x, i = threadIdx.x;
    rowv[i] = mb[m * H + i];
    __syncthreads();
    float ak = 0.f, av = 0.f;
    for (int j = 0; j < H; j++) {
        float x = rowv[j];
        ak = fmaf(x, ipw[(size_t)(H + i) * H + j], ak);
        av = fmaf(x, ipw[(size_t)(2 * H + i) * H + j], av);
    }
    kbuf[m * H + i] = ak + ipb[H + i];
    vbuf[m * H + i] = av + ipb[2 * H + i];
}

// ---------------- attention + classifier (one block per graph) ----------------

__launch_bounds__(128)
__global__ void attn_kernel(const float* __restrict__ psums, const int* __restrict__ gstart,
                            const float* __restrict__ kbuf, const float* __restrict__ vbuf,
                            const float* __restrict__ ipw, const float* __restrict__ ipb,
                            const float* __restrict__ out_w, const float* __restrict__ out_b,
                            const float* __restrict__ cw1, const float* __restrict__ cb1,
                            const float* __restrict__ cw2, const float* __restrict__ cb2,
                            float* __restrict__ out) {
    __shared__ float pooled[H], q[H], attn[H], z[2 * H], c1[H], sc[NHEAD * MM];
    int b = blockIdx.x, t = threadIdx.x;
    float cn = (float)max(gstart[b + 1] - gstart[b], 1);
    float pv = psums[b * H + t] / cn;
    pooled[t] = pv;
    z[t] = pv;
    __syncthreads();
    float a = 0.f;
    for (int j = 0; j < H; j++) a = fmaf(pooled[j], ipw[(size_t)t * H + j], a);
    q[t] = a + ipb[t];
    __syncthreads();
    for (int sidx = t; sidx < NHEAD * MM; sidx += 128) {
        int hh = sidx >> 6, m = sidx & 63;
        float s2 = 0.f;
        for (int d = 0; d < HDIM; d++)
            s2 = fmaf(q[hh * HDIM + d], kbuf[m * H + hh * HDIM + d], s2);
        sc[sidx] = s2 * 0.25f;   // 1/sqrt(16)
    }
    __syncthreads();
    if (t < NHEAD) {
        float mx = -1e30f;
        for (int m = 0; m < MM; m++) mx = fmaxf(mx, sc[t * MM + m]);
        float ssum = 0.f;
        for (int m = 0; m < MM; m++) { float e = expf(sc[t * MM + m] - mx); sc[t * MM + m] = e; ssum += e; }
        float inv = 1.f / ssum;
        for (int m = 0; m < MM; m++) sc[t * MM + m] *= inv;
    }
    __syncthreads();
    {
        int hh = t >> 4;
        float a2 = 0.f;
        for (int m = 0; m < MM; m++) a2 = fmaf(sc[hh * MM + m], vbuf[m * H + t], a2);
        attn[t] = a2;
    }
    __syncthreads();
    float mm = 0.f;
    for (int j = 0; j < H; j++) mm = fmaf(attn[j], out_w[(size_t)t * H + j], mm);
    z[H + t] = mm + out_b[t];
    __syncthreads();
    float cc = 0.f;
    for (int j = 0; j < 2 * H; j++) cc = fmaf(z[j], cw1[(size_t)j * H + t], cc);
    c1[t] = fmaxf(cc + cb1[t], 0.f);
    __syncthreads();
    if (t < CC) {
        float o = 0.f;
        for (int j = 0; j < H; j++) o = fmaf(c1[j], cw2[j * CC + t], o);
        out[b * CC + t] = o + cb2[t];
    }
}

// ---------------- launch ----------------

extern "C" void kernel_launch(void* const* d_in, const int* in_sizes, int n_in,
                              void* d_out, int out_size, void* d_ws, size_t ws_size,
                              hipStream_t stream) {
    const float* x      = (const float*)d_in[0];
    const int*   eidx   = (const int*)d_in[1];
    const int*   batch  = (const int*)d_in[2];
    const float* w1     = (const float*)d_in[3];
    const float* b1     = (const float*)d_in[4];
    const float* ln_g   = (const float*)d_in[5];
    const float* ln_b   = (const float*)d_in[6];
    const float* gw1    = (const float*)d_in[7];
    const float* gb1    = (const float*)d_in[8];
    const float* gw2    = (const float*)d_in[9];
    const float* gb2    = (const float*)d_in[10];
    const float* gw3    = (const float*)d_in[11];
    const float* gb3    = (const float*)d_in[12];
    const float* memb   = (const float*)d_in[13];
    const float* ipw    = (const float*)d_in[14];
    const float* ipb    = (const float*)d_in[15];
    const float* out_w  = (const float*)d_in[16];
    const float* out_b  = (const float*)d_in[17];
    const float* cw1    = (const float*)d_in[18];
    const float* cb1    = (const float*)d_in[19];
    const float* cw2    = (const float*)d_in[20];
    const float* cb2    = (const float*)d_in[21];

    const int* row = eidx;
    const int* col = eidx + EE;

    char* ws = (char*)d_ws;
    size_t off = 0;
    auto alloc = [&](size_t bytes) -> void* {
        void* p = ws + off;
        off += (bytes + 255) & ~(size_t)255;
        return p;
    };
    float* h_cur  = (float*)alloc((size_t)NN * H * 4);
    float* h_tmp  = (float*)alloc((size_t)NN * H * 4);
    char*  zbeg   = ws + off;
    int*   degcnt = (int*)alloc((size_t)NN * 4);
    float* psums  = (float*)alloc((size_t)BB * H * 4);
    size_t zbytes = (size_t)((ws + off) - zbeg);
    float* dis    = (float*)alloc((size_t)NN * 4);
    int*   offs   = (int*)alloc((size_t)NN * 4);
    int*   cursor = (int*)alloc((size_t)NN * 4);
    int*   csr    = (int*)alloc((size_t)EE * 4);
    int*   bsums  = (int*)alloc(256);
    int*   gstart = (int*)alloc((size_t)(BB + 1) * 4);
    float* kbuf   = (float*)alloc((size_t)MM * H * 4);
    float* vbuf   = (float*)alloc((size_t)MM * H * 4);
    _Float16* wf1 = (_Float16*)alloc((size_t)2 * DIN * H * 2);   // 256 KB (hi+lo)
    _Float16* wfg1 = (_Float16*)alloc((size_t)2 * H * H * 2);    // 128 KB
    _Float16* wfg2 = (_Float16*)alloc((size_t)2 * H * H * 2);
    _Float16* wfg3 = (_Float16*)alloc((size_t)2 * H * H * 2);
    (void)ws_size; (void)in_sizes; (void)n_in; (void)out_size;

    hipMemsetAsync(zbeg, 0, zbytes, stream);

    // W-split precompute (tiny)
    wsplit<<<(DIN / 32) * 8, 64, 0, stream>>>(w1, wf1, DIN / 32);
    wsplit<<<(H / 32) * 8, 64, 0, stream>>>(gw1, wfg1, H / 32);
    wsplit<<<(H / 32) * 8, 64, 0, stream>>>(gw2, wfg2, H / 32);
    wsplit<<<(H / 32) * 8, 64, 0, stream>>>(gw3, wfg3, H / 32);

    count_deg<<<(EE + 255) / 256, 256, 0, stream>>>(col, degcnt);
    scan_a<<<NB, 256, 0, stream>>>(degcnt, offs, bsums);
    scan_b<<<1, 64, 0, stream>>>(bsums);
    scan_c<<<(NN + 255) / 256, 256, 0, stream>>>(offs, bsums, degcnt, cursor, dis);
    fill_csr<<<(EE + 255) / 256, 256, 0, stream>>>(row, col, cursor, csr);
    graph_bounds<<<(NN + 255) / 256, 256, 0, stream>>>(batch, gstart);

    const int LGRID = (NN + 63) / 64;   // 782
    const int AGRID = (NN + 7) / 8;     // 6250

    // feature transform; output pre-scaled by dis (feeds agg layer 1)
    mfma_linear<DIN, true, true><<<LGRID, 256, 0, stream>>>(x, wf1, b1, ln_g, ln_b, dis, h_cur);

    // GCN layer 1
    agg_kernel<<<AGRID, 256, 0, stream>>>(h_cur, offs, degcnt, csr, dis, h_tmp);
    mfma_linear<H, false, true><<<LGRID, 256, 0, stream>>>(h_tmp, wfg1, gb1, nullptr, nullptr, dis, h_cur);
    // GCN layer 2
    agg_kernel<<<AGRID, 256, 0, stream>>>(h_cur, offs, degcnt, csr, dis, h_tmp);
    mfma_linear<H, false, true><<<LGRID, 256, 0, stream>>>(h_tmp, wfg2, gb2, nullptr, nullptr, dis, h_cur);
    // GCN layer 3 (unscaled output -> pool)
    agg_kernel<<<AGRID, 256, 0, stream>>>(h_cur, offs, degcnt, csr, dis, h_tmp);
    mfma_linear<H, false, false><<<LGRID, 256, 0, stream>>>(h_tmp, wfg3, gb3, nullptr, nullptr, dis, h_cur);

    pool2_kernel<<<(NN + PCHUNK - 1) / PCHUNK, PCHUNK, 0, stream>>>(h_cur, batch, psums);
    kv_kernel<<<MM, H, 0, stream>>>(memb, ipw, ipb, kbuf, vbuf);
    attn_kernel<<<BB, H, 0, stream>>>(psums, gstart, kbuf, vbuf, ipw, ipb, out_w, out_b,
                                      cw1, cb1, cw2, cb2, (float*)d_out);
}